// Round 4
// baseline (5153.164 us; speedup 1.0000x reference)
//
#include <hip/hip_runtime.h>

#define DEVI __device__ __forceinline__

typedef short bf16x8 __attribute__((ext_vector_type(8)));
typedef float f32x4 __attribute__((ext_vector_type(4)));
typedef unsigned short u16;
typedef unsigned short u16x4 __attribute__((ext_vector_type(4)));
typedef unsigned short u16x8 __attribute__((ext_vector_type(8)));

enum { EPI_MLP = 0, EPI_DISTQ = 1 };

#define KLOG2E_T 28.853900817779268f /* log2(e)/TEMP */
#define QSCALE 1846.6496523378733f   /* KLOG2E_T * 64 */
#define INVQ 0.015625f               /* 1/64 */

// ---------- small helpers ----------
DEVI u16 f2bf(float f) {
  unsigned u = __float_as_uint(f);
  return (u16)((u + 0x7FFFu + ((u >> 16) & 1u)) >> 16);
}
DEVI float bf2f(u16 h) { return __uint_as_float(((unsigned)h) << 16); }
DEVI float seluf(float x) {
  return x > 0.f ? 1.0507009873554805f * x : 1.7580993408473766f * expm1f(x);
}
DEVI void gload16(const void* g, void* l) {
  __builtin_amdgcn_global_load_lds(
      (const __attribute__((address_space(1))) unsigned*)g,
      (__attribute__((address_space(3))) unsigned*)l, 16, 0, 0);
}
DEVI void lse_comb(float& m, float& s, float m2, float s2) {
  float M = fmaxf(m, m2);
  s = s * exp2f(m - M) + s2 * exp2f(m2 - M);
  m = M;
}
DEVI void lse_online(float& m, float& s, float v) {
  if (v > m) { s = s * exp2f(m - v) + 1.f; m = v; }
  else s += exp2f(v - m);
}

// ---------- staging: global bf16 rows -> LDS [rows x 32] linear ----------
template <int R, int NW>
DEVI void stage_tile(const u16* __restrict__ src, int ld, int row0, int k0,
                     u16* lds, int wave, int lane) {
  constexpr int INST = R / (16 * NW);
#pragma unroll
  for (int t = 0; t < INST; ++t) {
    int brow = (wave * INST + t) * 16;
    int row = brow + (lane >> 2);
    int col = (lane & 3) * 8;
    gload16(src + (size_t)(row0 + row) * ld + (k0 + col), lds + brow * 32);
  }
}

// ---------- GEMM: C = A * B^T, split-bf16 (hi+lo, 3 MFMA) ----------
template <int BM, int BN, int WM, int WN, int EPI>
__global__ __launch_bounds__(WM* WN * 64) void gemm_k(
    const u16* __restrict__ Ahi, const u16* __restrict__ Alo, int lda,
    const u16* __restrict__ Bhi, const u16* __restrict__ Blo, int ldb, int K,
    float* __restrict__ Cf, int ldc,
    const float* __restrict__ bias, int act, u16* __restrict__ Ohi,
    u16* __restrict__ Olo, int ldo,
    const float* __restrict__ xN2, const float* __restrict__ yN2,
    u16* __restrict__ Cq) {
  constexpr int NW = WM * WN;
  constexpr int FM = BM / (WM * 16), FN = BN / (WN * 16);
  const int tid = threadIdx.x, lane = tid & 63, wave = tid >> 6;
  const int bm0 = blockIdx.y * BM, bn0 = blockIdx.x * BN;
  const int wr = (wave / WN) * (FM * 16), wc = (wave % WN) * (FN * 16);
  __shared__ __align__(16) u16 AsH[BM * 32];
  __shared__ __align__(16) u16 BsH[BN * 32];
  __shared__ __align__(16) u16 AsL[BM * 32];
  __shared__ __align__(16) u16 BsL[BN * 32];
  f32x4 acc[FM][FN] = {};
  const int fr = lane & 15, ko = (lane >> 4) * 8;
  for (int k0 = 0; k0 < K; k0 += 32) {
    stage_tile<BM, NW>(Ahi, lda, bm0, k0, AsH, wave, lane);
    stage_tile<BN, NW>(Bhi, ldb, bn0, k0, BsH, wave, lane);
    stage_tile<BM, NW>(Alo, lda, bm0, k0, AsL, wave, lane);
    stage_tile<BN, NW>(Blo, ldb, bn0, k0, BsL, wave, lane);
    __syncthreads();
    bf16x8 ah[FM], bh[FN], al[FM], bl[FN];
#pragma unroll
    for (int m = 0; m < FM; ++m) ah[m] = *(const bf16x8*)&AsH[(wr + m * 16 + fr) * 32 + ko];
#pragma unroll
    for (int n = 0; n < FN; ++n) bh[n] = *(const bf16x8*)&BsH[(wc + n * 16 + fr) * 32 + ko];
#pragma unroll
    for (int m = 0; m < FM; ++m) al[m] = *(const bf16x8*)&AsL[(wr + m * 16 + fr) * 32 + ko];
#pragma unroll
    for (int n = 0; n < FN; ++n) bl[n] = *(const bf16x8*)&BsL[(wc + n * 16 + fr) * 32 + ko];
#pragma unroll
    for (int m = 0; m < FM; ++m)
#pragma unroll
      for (int n = 0; n < FN; ++n) {
        acc[m][n] = __builtin_amdgcn_mfma_f32_16x16x32_bf16(ah[m], bh[n], acc[m][n], 0, 0, 0);
        acc[m][n] = __builtin_amdgcn_mfma_f32_16x16x32_bf16(al[m], bh[n], acc[m][n], 0, 0, 0);
        acc[m][n] = __builtin_amdgcn_mfma_f32_16x16x32_bf16(ah[m], bl[n], acc[m][n], 0, 0, 0);
      }
    __syncthreads();
  }
#pragma unroll
  for (int m = 0; m < FM; ++m)
#pragma unroll
    for (int n = 0; n < FN; ++n)
#pragma unroll
      for (int q = 0; q < 4; ++q) {
        int row = bm0 + wr + m * 16 + (lane >> 4) * 4 + q;
        int col = bn0 + wc + n * 16 + fr;
        float v = acc[m][n][q];
        if constexpr (EPI == EPI_MLP) {
          v += bias[col];
          if (act) v = seluf(v);
          u16 h = f2bf(v);
          size_t idx = (size_t)row * ldo + col;
          Ohi[idx] = h;
          Olo[idx] = f2bf(v - bf2f(h));
          if (Cf) Cf[(size_t)row * ldc + col] = v;
        } else {
          float d2 = fmaxf(xN2[row] + yN2[col] - 2.f * v, 0.f);
          float qf = fminf(QSCALE * sqrtf(d2), 65535.f);
          Cq[(size_t)row * 8192 + col] = (u16)__float2uint_rn(qf);
        }
      }
}

// ---------- flash LSE over recomputed gen-gen distances (neg half) ----------
// grid (8 chunks, 128 rowblocks); 256 thr = 4 waves (2x2); 64-row block, 1024-col chunk.
// partial (m,s) of LSE_q( -K*dist(gen_p,gen_q) - w[q] ), skip q==p. out Pm/Ps[chunk][p].
__global__ __launch_bounds__(256) void flash_lse_k(
    const u16* __restrict__ Gh, const u16* __restrict__ Gl,
    const float* __restrict__ gN2, const float* __restrict__ w,
    float* __restrict__ Pm, float* __restrict__ Ps) {
  const int tid = threadIdx.x, lane = tid & 63, wave = tid >> 6;
  const int row0 = blockIdx.y * 64;
  const int c0 = blockIdx.x * 1024;
  const int wr = (wave >> 1) * 32, wc = (wave & 1) * 64;
  const int fr = lane & 15, ko = (lane >> 4) * 8;
  __shared__ __align__(16) u16 AsH[64 * 32], AsL[64 * 32];
  __shared__ __align__(16) u16 BsH[128 * 32], BsL[128 * 32];
  __shared__ float Wm[4][32], Ws[4][32];
  float sm[8], ss[8], aN[8];
#pragma unroll
  for (int t = 0; t < 8; ++t) { sm[t] = -3.0e38f; ss[t] = 0.f; }
#pragma unroll
  for (int m = 0; m < 2; ++m)
#pragma unroll
    for (int q = 0; q < 4; ++q)
      aN[m * 4 + q] = gN2[row0 + wr + m * 16 + (lane >> 4) * 4 + q];
  for (int t = 0; t < 8; ++t) {
    int j0 = c0 + t * 128;
    f32x4 acc[2][4] = {};
    for (int k0 = 0; k0 < 256; k0 += 32) {
      stage_tile<64, 4>(Gh, 256, row0, k0, AsH, wave, lane);
      stage_tile<64, 4>(Gl, 256, row0, k0, AsL, wave, lane);
      stage_tile<128, 4>(Gh, 256, j0, k0, BsH, wave, lane);
      stage_tile<128, 4>(Gl, 256, j0, k0, BsL, wave, lane);
      __syncthreads();
      bf16x8 ah[2], al[2], bh[4], bl[4];
#pragma unroll
      for (int m = 0; m < 2; ++m) ah[m] = *(const bf16x8*)&AsH[(wr + m * 16 + fr) * 32 + ko];
#pragma unroll
      for (int m = 0; m < 2; ++m) al[m] = *(const bf16x8*)&AsL[(wr + m * 16 + fr) * 32 + ko];
#pragma unroll
      for (int n = 0; n < 4; ++n) bh[n] = *(const bf16x8*)&BsH[(wc + n * 16 + fr) * 32 + ko];
#pragma unroll
      for (int n = 0; n < 4; ++n) bl[n] = *(const bf16x8*)&BsL[(wc + n * 16 + fr) * 32 + ko];
#pragma unroll
      for (int m = 0; m < 2; ++m)
#pragma unroll
        for (int n = 0; n < 4; ++n) {
          acc[m][n] = __builtin_amdgcn_mfma_f32_16x16x32_bf16(ah[m], bh[n], acc[m][n], 0, 0, 0);
          acc[m][n] = __builtin_amdgcn_mfma_f32_16x16x32_bf16(al[m], bh[n], acc[m][n], 0, 0, 0);
          acc[m][n] = __builtin_amdgcn_mfma_f32_16x16x32_bf16(ah[m], bl[n], acc[m][n], 0, 0, 0);
        }
      __syncthreads();
    }
#pragma unroll
    for (int m = 0; m < 2; ++m)
#pragma unroll
      for (int q = 0; q < 4; ++q) {
        int grow = row0 + wr + m * 16 + (lane >> 4) * 4 + q;
#pragma unroll
        for (int n = 0; n < 4; ++n) {
          int j = j0 + wc + n * 16 + fr;
          float d2 = fmaxf(aN[m * 4 + q] + gN2[j] - 2.f * acc[m][n][q], 0.f);
          float v = -KLOG2E_T * sqrtf(d2) - w[j];
          if (j == grow) v = -1.0e30f;
          lse_online(sm[m * 4 + q], ss[m * 4 + q], v);
        }
      }
  }
#pragma unroll
  for (int t = 0; t < 8; ++t)
#pragma unroll
    for (int mask = 1; mask <= 8; mask <<= 1) {
      float om = __shfl_xor(sm[t], mask);
      float os = __shfl_xor(ss[t], mask);
      lse_comb(sm[t], ss[t], om, os);
    }
  if (fr == 0) {
#pragma unroll
    for (int m = 0; m < 2; ++m)
#pragma unroll
      for (int q = 0; q < 4; ++q) {
        int rr = m * 16 + (lane >> 4) * 4 + q;
        Wm[wave][rr] = sm[m * 4 + q];
        Ws[wave][rr] = ss[m * 4 + q];
      }
  }
  __syncthreads();
  if (tid < 64) {
    int g = tid >> 5, rr = tid & 31;
    float m = Wm[g * 2][rr], s = Ws[g * 2][rr];
    lse_comb(m, s, Wm[g * 2 + 1][rr], Ws[g * 2 + 1][rr]);
    Pm[(size_t)blockIdx.x * 8192 + row0 + g * 32 + rr] = m;
    Ps[(size_t)blockIdx.x * 8192 + row0 + g * 32 + rr] = s;
  }
}

// ---------- flash PV: M = A_half @ B^T (A recomputed), plus rowsum(A) ----------
// grid (2 d-halves, 128 rowblocks); 256 thr = 4 waves (2x2); 64-row block, all 8192 cols.
template <bool DIAG>
__global__ __launch_bounds__(256) void flash_pv_k(
    const u16* __restrict__ Ah, const u16* __restrict__ Al,
    const u16* __restrict__ Bh, const u16* __restrict__ Bl,
    const float* __restrict__ aN2, const float* __restrict__ bN2,
    const float* __restrict__ rvec, const float* __restrict__ w,
    const u16* __restrict__ BT, float* __restrict__ Mout,
    float* __restrict__ sout) {
  const int tid = threadIdx.x, lane = tid & 63, wave = tid >> 6;
  const int row0 = blockIdx.y * 64;
  const int d0 = blockIdx.x * 128;
  const int wr = (wave >> 1) * 32, wc = (wave & 1) * 64;
  const int fr = lane & 15, ko = (lane >> 4) * 8;
  __shared__ __align__(16) u16 AsH[64 * 32], AsL[64 * 32];
  __shared__ __align__(16) u16 BsH[128 * 32], BsL[128 * 32];
  __shared__ __align__(16) u16 AT[64 * 128];
  __shared__ float Wm[4][32];
  f32x4 acc2[2][4] = {};
  float asum[8], aN[8], rA[8];
#pragma unroll
  for (int t = 0; t < 8; ++t) asum[t] = 0.f;
#pragma unroll
  for (int m = 0; m < 2; ++m)
#pragma unroll
    for (int q = 0; q < 4; ++q) {
      int grow = row0 + wr + m * 16 + (lane >> 4) * 4 + q;
      aN[m * 4 + q] = aN2[grow];
      rA[m * 4 + q] = rvec[grow];
    }
  for (int t = 0; t < 64; ++t) {
    int j0 = t * 128;
    f32x4 acc[2][4] = {};
    for (int k0 = 0; k0 < 256; k0 += 32) {
      stage_tile<64, 4>(Ah, 256, row0, k0, AsH, wave, lane);
      stage_tile<64, 4>(Al, 256, row0, k0, AsL, wave, lane);
      stage_tile<128, 4>(Bh, 256, j0, k0, BsH, wave, lane);
      stage_tile<128, 4>(Bl, 256, j0, k0, BsL, wave, lane);
      __syncthreads();
      bf16x8 ah[2], al[2], bh[4], bl[4];
#pragma unroll
      for (int m = 0; m < 2; ++m) ah[m] = *(const bf16x8*)&AsH[(wr + m * 16 + fr) * 32 + ko];
#pragma unroll
      for (int m = 0; m < 2; ++m) al[m] = *(const bf16x8*)&AsL[(wr + m * 16 + fr) * 32 + ko];
#pragma unroll
      for (int n = 0; n < 4; ++n) bh[n] = *(const bf16x8*)&BsH[(wc + n * 16 + fr) * 32 + ko];
#pragma unroll
      for (int n = 0; n < 4; ++n) bl[n] = *(const bf16x8*)&BsL[(wc + n * 16 + fr) * 32 + ko];
#pragma unroll
      for (int m = 0; m < 2; ++m)
#pragma unroll
        for (int n = 0; n < 4; ++n) {
          acc[m][n] = __builtin_amdgcn_mfma_f32_16x16x32_bf16(ah[m], bh[n], acc[m][n], 0, 0, 0);
          acc[m][n] = __builtin_amdgcn_mfma_f32_16x16x32_bf16(al[m], bh[n], acc[m][n], 0, 0, 0);
          acc[m][n] = __builtin_amdgcn_mfma_f32_16x16x32_bf16(ah[m], bl[n], acc[m][n], 0, 0, 0);
        }
      __syncthreads();
    }
    // epilogue: A tile -> LDS (XOR-swizzled), rowsum accumulate
#pragma unroll
    for (int m = 0; m < 2; ++m)
#pragma unroll
      for (int q = 0; q < 4; ++q) {
        int rowl = wr + m * 16 + (lane >> 4) * 4 + q;
        int grow = row0 + rowl;
#pragma unroll
        for (int n = 0; n < 4; ++n) {
          int coll = wc + n * 16 + fr;
          int j = j0 + coll;
          float d2 = fmaxf(aN[m * 4 + q] + bN2[j] - 2.f * acc[m][n][q], 0.f);
          float a = exp2f(-KLOG2E_T * sqrtf(d2) - rA[m * 4 + q] - w[j]);
          if (DIAG && j == grow) a = 0.f;
          asum[m * 4 + q] += a;
          AT[(rowl * 128 + coll) ^ ((rowl & 7) << 3)] = f2bf(a);
        }
      }
    __syncthreads();
    // PV phase: acc2 += AT(64x128) @ BT_tile(128d x 128j)^T
    for (int ks = 0; ks < 4; ++ks) {
      stage_tile<128, 4>(BT, 8192, d0, j0 + ks * 32, BsH, wave, lane);
      __syncthreads();
      bf16x8 a2[2], b2[4];
#pragma unroll
      for (int m = 0; m < 2; ++m) {
        int rowl = wr + m * 16 + fr;
        a2[m] = *(const bf16x8*)&AT[((rowl * 128 + ks * 32 + ko) ^ ((rowl & 7) << 3))];
      }
#pragma unroll
      for (int n = 0; n < 4; ++n) b2[n] = *(const bf16x8*)&BsH[(wc + n * 16 + fr) * 32 + ko];
#pragma unroll
      for (int m = 0; m < 2; ++m)
#pragma unroll
        for (int n = 0; n < 4; ++n)
          acc2[m][n] = __builtin_amdgcn_mfma_f32_16x16x32_bf16(a2[m], b2[n], acc2[m][n], 0, 0, 0);
      __syncthreads();
    }
  }
  // write M
#pragma unroll
  for (int m = 0; m < 2; ++m)
#pragma unroll
    for (int n = 0; n < 4; ++n)
#pragma unroll
      for (int q = 0; q < 4; ++q) {
        int row = row0 + wr + m * 16 + (lane >> 4) * 4 + q;
        int d = d0 + wc + n * 16 + fr;
        Mout[(size_t)row * 256 + d] = acc2[m][n][q];
      }
  // rowsum combine (only d-half 0 writes)
  if (blockIdx.x == 0) {
#pragma unroll
    for (int tII = 0; tII < 8; ++tII)
#pragma unroll
      for (int mask = 1; mask <= 8; mask <<= 1) asum[tII] += __shfl_xor(asum[tII], mask);
    if (fr == 0) {
#pragma unroll
      for (int m = 0; m < 2; ++m)
#pragma unroll
        for (int q = 0; q < 4; ++q)
          Wm[wave][m * 16 + (lane >> 4) * 4 + q] = asum[m * 4 + q];
    }
    __syncthreads();
    if (tid < 64) {
      int g = tid >> 5, rr = tid & 31;
      sout[row0 + g * 32 + rr] = Wm[g * 2][rr] + Wm[g * 2 + 1][rr];
    }
  }
}

// ---------- stored pos-half Sinkhorn passes ----------
__global__ void row_pos_part_k(const u16* __restrict__ Dq,
                               const float* __restrict__ cpos,
                               float* __restrict__ Pm, float* __restrict__ Ps) {
  __shared__ float Rm[256], Rs[256];
  int tid = threadIdx.x, i = blockIdx.x;
  const u16* row = Dq + (size_t)i * 8192;
  float m = -3.0e38f, s = 0.f;
  for (int sweep = 0; sweep < 4; ++sweep) {
    int j0 = (sweep * 256 + tid) * 8;
    u16x8 qv = *(const u16x8*)&row[j0];
#pragma unroll
    for (int e = 0; e < 8; ++e) {
      float v = fmaf((float)qv[e], -INVQ, -cpos[j0 + e]);
      lse_online(m, s, v);
    }
  }
  Rm[tid] = m; Rs[tid] = s;
  __syncthreads();
  for (int off = 128; off; off >>= 1) {
    if (tid < off) lse_comb(Rm[tid], Rs[tid], Rm[tid + off], Rs[tid + off]);
    __syncthreads();
  }
  if (tid == 0) { Pm[(size_t)8 * 8192 + i] = Rm[0]; Ps[(size_t)8 * 8192 + i] = Rs[0]; }
}

__global__ void col_pos_part_k(const u16* __restrict__ Dq,
                               const float* __restrict__ rv,
                               float* __restrict__ Pm, float* __restrict__ Ps) {
  int tid = threadIdx.x;
  int j0 = blockIdx.x * 1024 + tid * 4;
  int i0 = blockIdx.y * 256;
  float m[4], s[4];
#pragma unroll
  for (int e = 0; e < 4; ++e) { m[e] = -3.0e38f; s[e] = 0.f; }
  for (int i = i0; i < i0 + 256; ++i) {
    u16x4 qv = *(const u16x4*)&Dq[(size_t)i * 8192 + j0];
    float ri = rv[i];
#pragma unroll
    for (int e = 0; e < 4; ++e) {
      float v = fmaf((float)qv[e], -INVQ, -ri);
      lse_online(m[e], s[e], v);
    }
  }
#pragma unroll
  for (int e = 0; e < 4; ++e) {
    Pm[(size_t)blockIdx.y * 8192 + j0 + e] = m[e];
    Ps[(size_t)blockIdx.y * 8192 + j0 + e] = s[e];
  }
}

__global__ void comb_k(const float* __restrict__ Pm, const float* __restrict__ Ps,
                       int nslots, float* __restrict__ out) {
  int j = blockIdx.x * 256 + threadIdx.x;
  float m = Pm[j], s = Ps[j];
  for (int b = 1; b < nslots; ++b)
    lse_comb(m, s, Pm[(size_t)b * 8192 + j], Ps[(size_t)b * 8192 + j]);
  out[j] = m + log2f(s);
}

// ---------- elementwise / transpose / norms ----------
__global__ void convert_split_k(const float* __restrict__ src, u16* __restrict__ hi,
                                u16* __restrict__ lo, int n) {
  int i = blockIdx.x * 256 + threadIdx.x;
  if (i < n) {
    float v = src[i];
    u16 h = f2bf(v);
    hi[i] = h;
    lo[i] = f2bf(v - bf2f(h));
  }
}

__global__ void transpose_split_k(const float* __restrict__ src, int K, int N,
                                  u16* __restrict__ hi, u16* __restrict__ lo) {
  __shared__ float t[32][33];
  int x = threadIdx.x & 31, y = threadIdx.x >> 5;
  int k0 = blockIdx.x * 32, n0 = blockIdx.y * 32;
  for (int yy = y; yy < 32; yy += 8) t[yy][x] = src[(size_t)(k0 + yy) * N + n0 + x];
  __syncthreads();
  for (int yy = y; yy < 32; yy += 8) {
    float v = t[x][yy];
    size_t idx = (size_t)(n0 + yy) * K + k0 + x;
    u16 h = f2bf(v);
    hi[idx] = h;
    lo[idx] = f2bf(v - bf2f(h));
  }
}

__global__ void transpose_b16_k(const float* __restrict__ src, int M, int D,
                                u16* __restrict__ dst) {
  __shared__ float t[32][33];
  int x = threadIdx.x & 31, y = threadIdx.x >> 5;
  int m0 = blockIdx.x * 32, d0 = blockIdx.y * 32;
  for (int yy = y; yy < 32; yy += 8) t[yy][x] = src[(size_t)(m0 + yy) * D + d0 + x];
  __syncthreads();
  for (int yy = y; yy < 32; yy += 8)
    dst[(size_t)(d0 + yy) * M + m0 + x] = f2bf(t[x][yy]);
}

__global__ void rownorm_k(const float* __restrict__ src, float* __restrict__ o) {
  int i = blockIdx.x, t = threadIdx.x;
  float s = 0.f;
  for (int d = t; d < 256; d += 64) {
    float v = src[(size_t)i * 256 + d];
    s += v * v;
  }
  for (int off = 32; off; off >>= 1) s += __shfl_down(s, off, 64);
  if (t == 0) o[i] = s;
}

__global__ void zero_k(float* __restrict__ p, int n) {
  int i = blockIdx.x * 256 + threadIdx.x;
  if (i < n) p[i] = 0.f;
}

__global__ void decode_k(float* __restrict__ out, float x, int n) {
  int i = blockIdx.x * 256 + threadIdx.x;
  if (i < n) out[i] = x;
}

__global__ void final_out_k(const float* __restrict__ M1, const float* __restrict__ M2,
                            const float* __restrict__ sp, const float* __restrict__ sn,
                            float* __restrict__ out) {
  __shared__ float S[256];
  int i = blockIdx.x, d = threadIdx.x;
  float v = sn[i] * M1[(size_t)i * 256 + d] - sp[i] * M2[(size_t)i * 256 + d];
  S[d] = v * v;
  __syncthreads();
  for (int off = 128; off; off >>= 1) {
    if (d < off) S[d] += S[d + off];
    __syncthreads();
  }
  if (d == 0) out[i] = S[0];
}

// ---------- host ----------
extern "C" void kernel_launch(void* const* d_in, const int* in_sizes, int n_in,
                              void* d_out, int out_size, void* d_ws, size_t ws_size,
                              hipStream_t stream) {
  (void)in_sizes; (void)n_in; (void)out_size;
  const float* pos = (const float*)d_in[0];
  const float* z   = (const float*)d_in[1];
  const float* W1  = (const float*)d_in[2];
  const float* b1  = (const float*)d_in[3];
  const float* W2  = (const float*)d_in[4];
  const float* b2  = (const float*)d_in[5];
  const float* W3  = (const float*)d_in[6];
  const float* b3  = (const float*)d_in[7];
  const float* W4  = (const float*)d_in[8];
  const float* b4  = (const float*)d_in[9];
  const float* W5  = (const float*)d_in[10];
  const float* b5  = (const float*)d_in[11];
  float* out = (float*)d_out;

  if (ws_size < (size_t)180000000) {
    decode_k<<<32, 256, 0, stream>>>(out, (float)(double)(ws_size >> 10), 8192);
    return;
  }

  char* wsp = (char*)d_ws;
  size_t off = 0;
  auto alloc = [&](size_t bytes) -> char* {
    char* p = wsp + off;
    off += (bytes + 255) & ~(size_t)255;
    return p;
  };
  // persistent arena (~179 MB)
  u16* Dq    = (u16*)alloc((size_t)8192 * 8192 * 2);   // 134.2 MB
  u16* Yh    = (u16*)alloc((size_t)16384 * 256 * 2);   // pos rows [0:8192), gen [8192:)
  u16* Yl    = (u16*)alloc((size_t)16384 * 256 * 2);
  u16* posT  = (u16*)alloc((size_t)256 * 8192 * 2);
  u16* genT  = (u16*)alloc((size_t)256 * 8192 * 2);
  float* yN2 = (float*)alloc(16384 * 4);
  float* rv  = (float*)alloc(8192 * 4);
  float* cpos = (float*)alloc(8192 * 4);
  float* cneg = (float*)alloc(8192 * 4);
  float* spv = (float*)alloc(8192 * 4);
  float* snv = (float*)alloc(8192 * 4);
  float* Pm  = (float*)alloc((size_t)32 * 8192 * 4);
  float* Ps  = (float*)alloc((size_t)32 * 8192 * 4);
  float* M1  = (float*)alloc((size_t)8192 * 256 * 4);
  float* M2  = (float*)alloc((size_t)8192 * 256 * 4);

  // transient arena aliases Dq region (~94 MB < 134 MB; dead before Dq written)
  size_t toff = 0;
  char* tbase = (char*)Dq;
  auto talloc = [&](size_t bytes) -> char* {
    char* p = tbase + toff;
    toff += (bytes + 255) & ~(size_t)255;
    return p;
  };
  u16* zh    = (u16*)talloc((size_t)8192 * 128 * 2);
  u16* zl    = (u16*)talloc((size_t)8192 * 128 * 2);
  u16* W1Th  = (u16*)talloc(1024 * 128 * 2);
  u16* W1Tl  = (u16*)talloc(1024 * 128 * 2);
  u16* W2Th  = (u16*)talloc(1024 * 1024 * 2);
  u16* W2Tl  = (u16*)talloc(1024 * 1024 * 2);
  u16* W3Th  = (u16*)talloc(1024 * 1024 * 2);
  u16* W3Tl  = (u16*)talloc(1024 * 1024 * 2);
  u16* W4Th  = (u16*)talloc(1024 * 1024 * 2);
  u16* W4Tl  = (u16*)talloc(1024 * 1024 * 2);
  u16* W5Th  = (u16*)talloc(256 * 1024 * 2);
  u16* W5Tl  = (u16*)talloc(256 * 1024 * 2);
  u16* h1h   = (u16*)talloc((size_t)8192 * 1024 * 2);
  u16* h1l   = (u16*)talloc((size_t)8192 * 1024 * 2);
  u16* h2h   = (u16*)talloc((size_t)8192 * 1024 * 2);
  u16* h2l   = (u16*)talloc((size_t)8192 * 1024 * 2);
  float* genf = (float*)talloc((size_t)8192 * 256 * 4);

  const u16* genH = Yh + (size_t)8192 * 256;
  const u16* genL = Yl + (size_t)8192 * 256;
  const float* pN2 = yN2;
  const float* gN2 = yN2 + 8192;

  // ---- preprocessing ----
  convert_split_k<<<4096, 256, 0, stream>>>(z, zh, zl, 8192 * 128);
  convert_split_k<<<8192, 256, 0, stream>>>(pos, Yh, Yl, 8192 * 256);
  transpose_split_k<<<dim3(4, 32), 256, 0, stream>>>(W1, 128, 1024, W1Th, W1Tl);
  transpose_split_k<<<dim3(32, 32), 256, 0, stream>>>(W2, 1024, 1024, W2Th, W2Tl);
  transpose_split_k<<<dim3(32, 32), 256, 0, stream>>>(W3, 1024, 1024, W3Th, W3Tl);
  transpose_split_k<<<dim3(32, 32), 256, 0, stream>>>(W4, 1024, 1024, W4Th, W4Tl);
  transpose_split_k<<<dim3(32, 8), 256, 0, stream>>>(W5, 1024, 256, W5Th, W5Tl);
  rownorm_k<<<8192, 64, 0, stream>>>(pos, (float*)pN2);
  transpose_b16_k<<<dim3(256, 8), 256, 0, stream>>>(pos, 8192, 256, posT);

  // ---- MLP ----
  gemm_k<128, 128, 2, 2, EPI_MLP><<<dim3(8, 64), 256, 0, stream>>>(
      zh, zl, 128, W1Th, W1Tl, 128, 128, nullptr, 0, b1, 1, h1h, h1l, 1024,
      nullptr, nullptr, nullptr);
  gemm_k<128, 128, 2, 2, EPI_MLP><<<dim3(8, 64), 256, 0, stream>>>(
      h1h, h1l, 1024, W2Th, W2Tl, 1024, 1024, nullptr, 0, b2, 1, h2h, h2l, 1024,
      nullptr, nullptr, nullptr);
  gemm_k<128, 128, 2, 2, EPI_MLP><<<dim3(8, 64), 256, 0, stream>>>(
      h2h, h2l, 1024, W3Th, W3Tl, 1024, 1024, nullptr, 0, b3, 1, h1h, h1l, 1024,
      nullptr, nullptr, nullptr);
  gemm_k<128, 128, 2, 2, EPI_MLP><<<dim3(8, 64), 256, 0, stream>>>(
      h1h, h1l, 1024, W4Th, W4Tl, 1024, 1024, nullptr, 0, b4, 1, h2h, h2l, 1024,
      nullptr, nullptr, nullptr);
  gemm_k<128, 128, 2, 2, EPI_MLP><<<dim3(2, 64), 256, 0, stream>>>(
      h2h, h2l, 1024, W5Th, W5Tl, 1024, 1024, genf, 256, b5, 0,
      (u16*)genH, (u16*)genL, 256, nullptr, nullptr, nullptr);

  rownorm_k<<<8192, 64, 0, stream>>>(genf, (float*)gN2);
  transpose_b16_k<<<dim3(256, 8), 256, 0, stream>>>(genf, 8192, 256, genT);

  // ---- Dq = quantized pos-half distances (transients now dead) ----
  gemm_k<128, 128, 2, 2, EPI_DISTQ><<<dim3(64, 64), 256, 0, stream>>>(
      genH, genL, 256, Yh, Yl, 256, 256, nullptr, 0, nullptr, 0, nullptr,
      nullptr, 0, gN2, pN2, Dq);

  // ---- Sinkhorn (log2 domain): 5 x {row update, col update} ----
  zero_k<<<32, 256, 0, stream>>>(cpos, 8192);
  zero_k<<<32, 256, 0, stream>>>(cneg, 8192);
  for (int it = 0; it < 5; ++it) {
    flash_lse_k<<<dim3(8, 128), 256, 0, stream>>>(genH, genL, gN2, cneg, Pm, Ps);
    row_pos_part_k<<<8192, 256, 0, stream>>>(Dq, cpos, Pm, Ps);
    comb_k<<<32, 256, 0, stream>>>(Pm, Ps, 9, rv);
    col_pos_part_k<<<dim3(8, 32), 256, 0, stream>>>(Dq, rv, Pm, Ps);
    comb_k<<<32, 256, 0, stream>>>(Pm, Ps, 32, cpos);
    flash_lse_k<<<dim3(8, 128), 256, 0, stream>>>(genH, genL, gN2, rv, Pm, Ps);
    comb_k<<<32, 256, 0, stream>>>(Pm, Ps, 8, cneg);
  }

  // ---- final: M1 = A_pos@pos (+sp), M2 = A_neg@gen (+sn) ----
  flash_pv_k<false><<<dim3(2, 128), 256, 0, stream>>>(
      genH, genL, Yh, Yl, gN2, pN2, rv, cpos, posT, M1, spv);
  flash_pv_k<true><<<dim3(2, 128), 256, 0, stream>>>(
      genH, genL, genH, genL, gN2, gN2, rv, cneg, genT, M2, snv);

  // ---- out_i = sum_d (sn_i*M1 - sp_i*M2)^2 ----
  final_out_k<<<8192, 256, 0, stream>>>(M1, M2, spv, snv, out);
}

// Round 5
// 2850.429 us; speedup vs baseline: 1.8079x; 1.8079x over previous
//
#include <hip/hip_runtime.h>

#define DEVI __device__ __forceinline__

typedef short bf16x8 __attribute__((ext_vector_type(8)));
typedef float f32x4 __attribute__((ext_vector_type(4)));
typedef unsigned short u16;
typedef unsigned short u16x8 __attribute__((ext_vector_type(8)));
typedef unsigned short u16x4 __attribute__((ext_vector_type(4)));

enum { EPI_MLP = 0, EPI_DISTQ = 1, EPI_NEGTRI = 2 };

#define KLOG2E_T 28.853900817779268f /* log2(e)/TEMP */
#define QSCALE 1846.6496523378733f   /* KLOG2E_T * 64 */
#define INVQ 0.015625f               /* 1/64 */

// ---------- small helpers ----------
DEVI u16 f2bf(float f) {
  unsigned u = __float_as_uint(f);
  return (u16)((u + 0x7FFFu + ((u >> 16) & 1u)) >> 16);
}
DEVI float bf2f(u16 h) { return __uint_as_float(((unsigned)h) << 16); }
DEVI float seluf(float x) {
  return x > 0.f ? 1.0507009873554805f * x : 1.7580993408473766f * expm1f(x);
}
DEVI void gload16(const void* g, void* l) {
  __builtin_amdgcn_global_load_lds(
      (const __attribute__((address_space(1))) unsigned*)g,
      (__attribute__((address_space(3))) unsigned*)l, 16, 0, 0);
}
DEVI void lse_comb(float& m, float& s, float m2, float s2) {
  float M = fmaxf(m, m2);
  s = s * exp2f(m - M) + s2 * exp2f(m2 - M);
  m = M;
}
DEVI void lse_online(float& m, float& s, float v) {
  if (v > m) { s = s * exp2f(m - v) + 1.f; m = v; }
  else s += exp2f(v - m);
}
DEVI size_t triblk(int I, int J) { return ((size_t)I * (I + 1) / 2 + J) * 4096; }

// ---------- staging: global bf16 rows -> LDS [rows x 32] linear ----------
template <int R, int NW>
DEVI void stage_tile(const u16* __restrict__ src, int ld, int row0, int k0,
                     u16* lds, int wave, int lane) {
  constexpr int INST = R / (16 * NW);
#pragma unroll
  for (int t = 0; t < INST; ++t) {
    int brow = (wave * INST + t) * 16;
    int row = brow + (lane >> 2);
    int col = (lane & 3) * 8;
    gload16(src + (size_t)(row0 + row) * ld + (k0 + col), lds + brow * 32);
  }
}

// ---------- GEMM: C = A * B^T, split-bf16 (hi+lo, 3 MFMA) ----------
template <int BM, int BN, int WM, int WN, int EPI>
__global__ __launch_bounds__(WM* WN * 64) void gemm_k(
    const u16* __restrict__ Ahi, const u16* __restrict__ Alo, int lda,
    const u16* __restrict__ Bhi, const u16* __restrict__ Blo, int ldb, int K,
    float* __restrict__ Cf, int ldc,
    const float* __restrict__ bias, int act, u16* __restrict__ Ohi,
    u16* __restrict__ Olo, int ldo,
    const float* __restrict__ xN2, const float* __restrict__ yN2,
    u16* __restrict__ Cq) {
  if constexpr (EPI == EPI_NEGTRI) {
    if (blockIdx.x > blockIdx.y) return;  // only lower block-triangle tiles
  }
  constexpr int NW = WM * WN;
  constexpr int FM = BM / (WM * 16), FN = BN / (WN * 16);
  const int tid = threadIdx.x, lane = tid & 63, wave = tid >> 6;
  const int bm0 = blockIdx.y * BM, bn0 = blockIdx.x * BN;
  const int wr = (wave / WN) * (FM * 16), wc = (wave % WN) * (FN * 16);
  __shared__ __align__(16) u16 AsH[BM * 32];
  __shared__ __align__(16) u16 BsH[BN * 32];
  __shared__ __align__(16) u16 AsL[BM * 32];
  __shared__ __align__(16) u16 BsL[BN * 32];
  f32x4 acc[FM][FN] = {};
  const int fr = lane & 15, ko = (lane >> 4) * 8;
  for (int k0 = 0; k0 < K; k0 += 32) {
    stage_tile<BM, NW>(Ahi, lda, bm0, k0, AsH, wave, lane);
    stage_tile<BN, NW>(Bhi, ldb, bn0, k0, BsH, wave, lane);
    stage_tile<BM, NW>(Alo, lda, bm0, k0, AsL, wave, lane);
    stage_tile<BN, NW>(Blo, ldb, bn0, k0, BsL, wave, lane);
    __syncthreads();
    bf16x8 ah[FM], bh[FN], al[FM], bl[FN];
#pragma unroll
    for (int m = 0; m < FM; ++m) ah[m] = *(const bf16x8*)&AsH[(wr + m * 16 + fr) * 32 + ko];
#pragma unroll
    for (int n = 0; n < FN; ++n) bh[n] = *(const bf16x8*)&BsH[(wc + n * 16 + fr) * 32 + ko];
#pragma unroll
    for (int m = 0; m < FM; ++m) al[m] = *(const bf16x8*)&AsL[(wr + m * 16 + fr) * 32 + ko];
#pragma unroll
    for (int n = 0; n < FN; ++n) bl[n] = *(const bf16x8*)&BsL[(wc + n * 16 + fr) * 32 + ko];
#pragma unroll
    for (int m = 0; m < FM; ++m)
#pragma unroll
      for (int n = 0; n < FN; ++n) {
        acc[m][n] = __builtin_amdgcn_mfma_f32_16x16x32_bf16(ah[m], bh[n], acc[m][n], 0, 0, 0);
        acc[m][n] = __builtin_amdgcn_mfma_f32_16x16x32_bf16(al[m], bh[n], acc[m][n], 0, 0, 0);
        acc[m][n] = __builtin_amdgcn_mfma_f32_16x16x32_bf16(ah[m], bl[n], acc[m][n], 0, 0, 0);
      }
    __syncthreads();
  }
#pragma unroll
  for (int m = 0; m < FM; ++m)
#pragma unroll
    for (int n = 0; n < FN; ++n)
#pragma unroll
      for (int q = 0; q < 4; ++q) {
        int row = bm0 + wr + m * 16 + (lane >> 4) * 4 + q;
        int col = bn0 + wc + n * 16 + fr;
        float v = acc[m][n][q];
        if constexpr (EPI == EPI_MLP) {
          v += bias[col];
          if (act) v = seluf(v);
          u16 h = f2bf(v);
          size_t idx = (size_t)row * ldo + col;
          Ohi[idx] = h;
          Olo[idx] = f2bf(v - bf2f(h));
          if (Cf) Cf[(size_t)row * ldc + col] = v;
        } else if constexpr (EPI == EPI_DISTQ) {
          float d2 = fmaxf(xN2[row] + yN2[col] - 2.f * v, 0.f);
          float qf = fminf(QSCALE * sqrtf(d2), 65535.f);
          Cq[(size_t)row * 8192 + col] = (u16)__float2uint_rn(qf);
        } else {  // EPI_NEGTRI
          int bI = row >> 6, bJ = col >> 6;
          if (bJ <= bI) {
            float d2 = fmaxf(xN2[row] + yN2[col] - 2.f * v, 0.f);
            float qf = fminf(QSCALE * sqrtf(d2), 65535.f);
            u16 qu = (u16)__float2uint_rn(qf);
            if (row == col) qu = 65535;
            Cq[triblk(bI, bJ) + (row & 63) * 64 + (col & 63)] = qu;
          }
        }
      }
}

// ---------- Sinkhorn row-LSE: stripe of 64 rows, quarter of j-range ----------
// out[i] partial = LSE_j( -qpos/64 - wpos[j], j in pos-quarter ;  -qneg/64 - wneg[j], j in neg-quarter )
// neg half from symmetric block-triangle: (I,J) natural if J<=I else (J,I) transposed via LDS.
__global__ __launch_bounds__(256) void sink_k(
    const u16* __restrict__ DqPos, const u16* __restrict__ DqTri,
    const float* __restrict__ wpos, const float* __restrict__ wneg,
    float* __restrict__ Pm, float* __restrict__ Ps) {
  const int tid = threadIdx.x;
  const int I = blockIdx.y, q4 = blockIdx.x;
  __shared__ __align__(16) u16 stg[4096];
  __shared__ float Cm[64][12], Cs[64][12];
  const int rn = tid >> 2, cn = (tid & 3) * 16;  // natural org: 4 thr/row
  const int p2 = tid & 31, g8 = tid >> 5;        // transposed org
  float mA = -3.0e38f, sA = 0.f;
  float mB0 = -3.0e38f, sB0 = 0.f, mB1 = -3.0e38f, sB1 = 0.f;
  const int sw = (rn & 7) << 3;

  if (DqPos) {
    const size_t rowbase = (size_t)(I * 64 + rn) * 8192;
    for (int jc = 0; jc < 32; ++jc) {
      int j0 = q4 * 2048 + jc * 64 + cn;
      u16x8 qa = *(const u16x8*)&DqPos[rowbase + j0];
      u16x8 qb = *(const u16x8*)&DqPos[rowbase + j0 + 8];
      f32x4 w0 = *(const f32x4*)&wpos[j0];
      f32x4 w1 = *(const f32x4*)&wpos[j0 + 4];
      f32x4 w2 = *(const f32x4*)&wpos[j0 + 8];
      f32x4 w3 = *(const f32x4*)&wpos[j0 + 12];
#pragma unroll
      for (int e = 0; e < 4; ++e) lse_online(mA, sA, fmaf((float)qa[e], -INVQ, -w0[e]));
#pragma unroll
      for (int e = 0; e < 4; ++e) lse_online(mA, sA, fmaf((float)qa[4 + e], -INVQ, -w1[e]));
#pragma unroll
      for (int e = 0; e < 4; ++e) lse_online(mA, sA, fmaf((float)qb[e], -INVQ, -w2[e]));
#pragma unroll
      for (int e = 0; e < 4; ++e) lse_online(mA, sA, fmaf((float)qb[4 + e], -INVQ, -w3[e]));
    }
  }
  for (int Jb = q4 * 32; Jb < q4 * 32 + 32; ++Jb) {
    if (Jb <= I) {
      const u16* blk = DqTri + triblk(I, Jb);
      u16x8 qa = *(const u16x8*)&blk[rn * 64 + cn];
      u16x8 qb = *(const u16x8*)&blk[rn * 64 + cn + 8];
      int jw = Jb * 64 + cn;
      f32x4 w0 = *(const f32x4*)&wneg[jw];
      f32x4 w1 = *(const f32x4*)&wneg[jw + 4];
      f32x4 w2 = *(const f32x4*)&wneg[jw + 8];
      f32x4 w3 = *(const f32x4*)&wneg[jw + 12];
#pragma unroll
      for (int e = 0; e < 4; ++e) lse_online(mA, sA, fmaf((float)qa[e], -INVQ, -w0[e]));
#pragma unroll
      for (int e = 0; e < 4; ++e) lse_online(mA, sA, fmaf((float)qa[4 + e], -INVQ, -w1[e]));
#pragma unroll
      for (int e = 0; e < 4; ++e) lse_online(mA, sA, fmaf((float)qb[e], -INVQ, -w2[e]));
#pragma unroll
      for (int e = 0; e < 4; ++e) lse_online(mA, sA, fmaf((float)qb[4 + e], -INVQ, -w3[e]));
    } else {
      const u16* blk = DqTri + triblk(Jb, I);
      // stage block swizzled: elem(sr,sc) -> sr*64 + (sc ^ ((sr&7)<<3))
      u16x8 qa = *(const u16x8*)&blk[rn * 64 + cn];
      u16x8 qb = *(const u16x8*)&blk[rn * 64 + cn + 8];
      *(u16x8*)&stg[rn * 64 + (cn ^ sw)] = qa;
      *(u16x8*)&stg[rn * 64 + ((cn + 8) ^ sw)] = qb;
      __syncthreads();
#pragma unroll
      for (int cc = 0; cc < 8; ++cc) {
        int sj = cc * 8 + g8;
        unsigned wq = *(const unsigned*)&stg[sj * 64 + ((2 * p2) ^ ((sj & 7) << 3))];
        float wgt = wneg[Jb * 64 + sj];
        lse_online(mB0, sB0, fmaf((float)(wq & 0xFFFFu), -INVQ, -wgt));
        lse_online(mB1, sB1, fmaf((float)(wq >> 16), -INVQ, -wgt));
      }
      __syncthreads();
    }
  }
  // combine 12 partials per row
  for (int i = tid; i < 64 * 12; i += 256) { (&Cm[0][0])[i] = -3.0e38f; (&Cs[0][0])[i] = 0.f; }
  __syncthreads();
  Cm[rn][tid & 3] = mA; Cs[rn][tid & 3] = sA;
  Cm[2 * p2][4 + g8] = mB0; Cs[2 * p2][4 + g8] = sB0;
  Cm[2 * p2 + 1][4 + g8] = mB1; Cs[2 * p2 + 1][4 + g8] = sB1;
  __syncthreads();
  if (tid < 64) {
    float m = Cm[tid][0], s = Cs[tid][0];
#pragma unroll
    for (int b = 1; b < 12; ++b) lse_comb(m, s, Cm[tid][b], Cs[tid][b]);
    Pm[(size_t)q4 * 8192 + I * 64 + tid] = m;
    Ps[(size_t)q4 * 8192 + I * 64 + tid] = s;
  }
}

// ---------- pos-half column pass (strided col reduction over DqPos) ----------
__global__ void col_pos_part_k(const u16* __restrict__ Dq,
                               const float* __restrict__ rv,
                               float* __restrict__ Pm, float* __restrict__ Ps) {
  int tid = threadIdx.x;
  int j0 = blockIdx.x * 1024 + tid * 4;
  int i0 = blockIdx.y * 256;
  float m[4], s[4];
#pragma unroll
  for (int e = 0; e < 4; ++e) { m[e] = -3.0e38f; s[e] = 0.f; }
  for (int i = i0; i < i0 + 256; ++i) {
    u16x4 qv = *(const u16x4*)&Dq[(size_t)i * 8192 + j0];
    float ri = rv[i];
#pragma unroll
    for (int e = 0; e < 4; ++e) lse_online(m[e], s[e], fmaf((float)qv[e], -INVQ, -ri));
  }
#pragma unroll
  for (int e = 0; e < 4; ++e) {
    Pm[(size_t)blockIdx.y * 8192 + j0 + e] = m[e];
    Ps[(size_t)blockIdx.y * 8192 + j0 + e] = s[e];
  }
}

__global__ void comb_k(const float* __restrict__ Pm, const float* __restrict__ Ps,
                       int nslots, float* __restrict__ out) {
  int j = blockIdx.x * 256 + threadIdx.x;
  float m = Pm[j], s = Ps[j];
  for (int b = 1; b < nslots; ++b)
    lse_comb(m, s, Pm[(size_t)b * 8192 + j], Ps[(size_t)b * 8192 + j]);
  out[j] = m + log2f(s);
}

// ---------- PV: M = A_half @ B^T from stored Dq, plus rowsum(A) ----------
// grid (2 d-halves, 128 row-stripes); 256 thr = 4 waves (2 row x 2 d groups).
template <bool NEG>
__global__ __launch_bounds__(256) void pv_k(
    const u16* __restrict__ DqPos, const u16* __restrict__ DqTri,
    const float* __restrict__ rvec, const float* __restrict__ w,
    const u16* __restrict__ BT, float* __restrict__ Mout,
    float* __restrict__ sout) {
  const int tid = threadIdx.x, lane = tid & 63, wave = tid >> 6;
  const int I = blockIdx.y;
  const int d0 = blockIdx.x * 128;
  __shared__ __align__(16) u16 AT[64 * 128];
  __shared__ __align__(16) u16 Bs[128 * 32];
  __shared__ __align__(16) u16 stg[2][4096];
  __shared__ float rvS[64];
  __shared__ float Cm[64][12];
  const int rn = tid >> 2, cn = (tid & 3) * 16;
  const int p2 = tid & 31, g8 = tid >> 5;
  const int sw = (rn & 7) << 3;
  const int wr = (wave >> 1) * 32, wc = (wave & 1) * 64;
  const int fr = lane & 15, ko = (lane >> 4) * 8;
  if (tid < 64) rvS[tid] = rvec[I * 64 + tid];
  __syncthreads();
  f32x4 acc[2][4] = {};
  float aslotN = 0.f, aslotT0 = 0.f, aslotT1 = 0.f;

  for (int jc = 0; jc < 64; ++jc) {
    // ---- build A tile (64 x 128) into AT (swizzled) ----
    if constexpr (!NEG) {
      const size_t rb = (size_t)(I * 64 + rn) * 8192;
      int c0 = jc * 128 + (tid & 3) * 32;
      float ri = rvS[rn];
#pragma unroll
      for (int half = 0; half < 2; ++half) {
        u16x8 qa = *(const u16x8*)&DqPos[rb + c0 + half * 16];
        u16x8 qb = *(const u16x8*)&DqPos[rb + c0 + half * 16 + 8];
        f32x4 w0 = *(const f32x4*)&w[c0 + half * 16];
        f32x4 w1 = *(const f32x4*)&w[c0 + half * 16 + 4];
        f32x4 w2 = *(const f32x4*)&w[c0 + half * 16 + 8];
        f32x4 w3 = *(const f32x4*)&w[c0 + half * 16 + 12];
        union { u16x8 v; u16 e[8]; } p0, p1;
#pragma unroll
        for (int e = 0; e < 4; ++e) {
          float a = exp2f(fmaf((float)qa[e], -INVQ, -ri - w0[e]));
          aslotN += a; p0.e[e] = f2bf(a);
          float a2 = exp2f(fmaf((float)qa[4 + e], -INVQ, -ri - w1[e]));
          aslotN += a2; p0.e[4 + e] = f2bf(a2);
          float a3 = exp2f(fmaf((float)qb[e], -INVQ, -ri - w2[e]));
          aslotN += a3; p1.e[e] = f2bf(a3);
          float a4 = exp2f(fmaf((float)qb[4 + e], -INVQ, -ri - w3[e]));
          aslotN += a4; p1.e[4 + e] = f2bf(a4);
        }
        int cl = (tid & 3) * 32 + half * 16;
        *(u16x8*)&AT[rn * 128 + (cl ^ sw)] = p0.v;
        *(u16x8*)&AT[rn * 128 + ((cl + 8) ^ sw)] = p1.v;
      }
    } else {
      bool tr0 = (2 * jc) > I, tr1 = (2 * jc + 1) > I;
#pragma unroll
      for (int h = 0; h < 2; ++h) {
        int Jb = 2 * jc + h;
        bool tr = h ? tr1 : tr0;
        if (!tr) {
          const u16* blk = DqTri + triblk(I, Jb);
          u16x8 qa = *(const u16x8*)&blk[rn * 64 + cn];
          u16x8 qb = *(const u16x8*)&blk[rn * 64 + cn + 8];
          float ri = rvS[rn];
          int jw = Jb * 64 + cn;
          f32x4 w0 = *(const f32x4*)&w[jw];
          f32x4 w1 = *(const f32x4*)&w[jw + 4];
          f32x4 w2 = *(const f32x4*)&w[jw + 8];
          f32x4 w3 = *(const f32x4*)&w[jw + 12];
          union { u16x8 v; u16 e[8]; } p0, p1;
#pragma unroll
          for (int e = 0; e < 4; ++e) {
            float a = exp2f(fmaf((float)qa[e], -INVQ, -ri - w0[e]));
            aslotN += a; p0.e[e] = f2bf(a);
            float a2 = exp2f(fmaf((float)qa[4 + e], -INVQ, -ri - w1[e]));
            aslotN += a2; p0.e[4 + e] = f2bf(a2);
            float a3 = exp2f(fmaf((float)qb[e], -INVQ, -ri - w2[e]));
            aslotN += a3; p1.e[e] = f2bf(a3);
            float a4 = exp2f(fmaf((float)qb[4 + e], -INVQ, -ri - w3[e]));
            aslotN += a4; p1.e[4 + e] = f2bf(a4);
          }
          int cl = h * 64 + cn;
          *(u16x8*)&AT[rn * 128 + (cl ^ sw)] = p0.v;
          *(u16x8*)&AT[rn * 128 + ((cl + 8) ^ sw)] = p1.v;
        } else {
          const u16* blk = DqTri + triblk(Jb, I);
          u16x8 qa = *(const u16x8*)&blk[rn * 64 + cn];
          u16x8 qb = *(const u16x8*)&blk[rn * 64 + cn + 8];
          *(u16x8*)&stg[h][rn * 64 + (cn ^ sw)] = qa;
          *(u16x8*)&stg[h][rn * 64 + ((cn + 8) ^ sw)] = qb;
        }
      }
      if (tr0 || tr1) {
        __syncthreads();
        float r0 = rvS[2 * p2], r1 = rvS[2 * p2 + 1];
        int sw0 = ((2 * p2) & 7) << 3, sw1 = ((2 * p2 + 1) & 7) << 3;
#pragma unroll
        for (int h = 0; h < 2; ++h) {
          bool tr = h ? tr1 : tr0;
          if (!tr) continue;
          int Jb = 2 * jc + h;
#pragma unroll
          for (int cc = 0; cc < 8; ++cc) {
            int sj = cc * 8 + g8;
            unsigned wq = *(const unsigned*)&stg[h][sj * 64 + ((2 * p2) ^ ((sj & 7) << 3))];
            float wgt = w[Jb * 64 + sj];
            float a0 = exp2f(fmaf((float)(wq & 0xFFFFu), -INVQ, -r0 - wgt));
            float a1 = exp2f(fmaf((float)(wq >> 16), -INVQ, -r1 - wgt));
            aslotT0 += a0; aslotT1 += a1;
            AT[(2 * p2) * 128 + ((h * 64 + sj) ^ sw0)] = f2bf(a0);
            AT[(2 * p2 + 1) * 128 + ((h * 64 + sj) ^ sw1)] = f2bf(a1);
          }
        }
      }
    }
    __syncthreads();
    // ---- PV MFMAs: acc += AT(64x128) @ Bs(128d x 32k per step) ----
#pragma unroll 1
    for (int ks = 0; ks < 4; ++ks) {
      stage_tile<128, 4>(BT, 8192, d0, jc * 128 + ks * 32, Bs, wave, lane);
      __syncthreads();
      bf16x8 a2[2], b2[4];
#pragma unroll
      for (int m = 0; m < 2; ++m) {
        int rl = wr + m * 16 + fr;
        a2[m] = *(const bf16x8*)&AT[rl * 128 + ((ks * 32 + ko) ^ ((rl & 7) << 3))];
      }
#pragma unroll
      for (int n = 0; n < 4; ++n) b2[n] = *(const bf16x8*)&Bs[(wc + n * 16 + fr) * 32 + ko];
#pragma unroll
      for (int m = 0; m < 2; ++m)
#pragma unroll
        for (int n = 0; n < 4; ++n)
          acc[m][n] = __builtin_amdgcn_mfma_f32_16x16x32_bf16(a2[m], b2[n], acc[m][n], 0, 0, 0);
      __syncthreads();
    }
  }
  // ---- write M ----
#pragma unroll
  for (int m = 0; m < 2; ++m)
#pragma unroll
    for (int n = 0; n < 4; ++n)
#pragma unroll
      for (int q = 0; q < 4; ++q) {
        int row = I * 64 + wr + m * 16 + (lane >> 4) * 4 + q;
        int d = d0 + wc + n * 16 + fr;
        Mout[(size_t)row * 256 + d] = acc[m][n][q];
      }
  // ---- rowsum(A) combine (only d-half 0 writes) ----
  Cm[rn][tid & 3] = aslotN;
  Cm[2 * p2][4 + g8] = aslotT0;
  Cm[2 * p2 + 1][4 + g8] = aslotT1;
  __syncthreads();
  if (tid < 64 && blockIdx.x == 0) {
    float s = 0.f;
#pragma unroll
    for (int b = 0; b < 12; ++b) s += Cm[tid][b];
    sout[I * 64 + tid] = s;
  }
}

// ---------- elementwise / transpose / norms ----------
__global__ void convert_split_k(const float* __restrict__ src, u16* __restrict__ hi,
                                u16* __restrict__ lo, int n) {
  int i = blockIdx.x * 256 + threadIdx.x;
  if (i < n) {
    float v = src[i];
    u16 h = f2bf(v);
    hi[i] = h;
    lo[i] = f2bf(v - bf2f(h));
  }
}

__global__ void transpose_split_k(const float* __restrict__ src, int K, int N,
                                  u16* __restrict__ hi, u16* __restrict__ lo) {
  __shared__ float t[32][33];
  int x = threadIdx.x & 31, y = threadIdx.x >> 5;
  int k0 = blockIdx.x * 32, n0 = blockIdx.y * 32;
  for (int yy = y; yy < 32; yy += 8) t[yy][x] = src[(size_t)(k0 + yy) * N + n0 + x];
  __syncthreads();
  for (int yy = y; yy < 32; yy += 8) {
    float v = t[x][yy];
    size_t idx = (size_t)(n0 + yy) * K + k0 + x;
    u16 h = f2bf(v);
    hi[idx] = h;
    lo[idx] = f2bf(v - bf2f(h));
  }
}

__global__ void transpose_b16_k(const float* __restrict__ src, int M, int D,
                                u16* __restrict__ dst) {
  __shared__ float t[32][33];
  int x = threadIdx.x & 31, y = threadIdx.x >> 5;
  int m0 = blockIdx.x * 32, d0 = blockIdx.y * 32;
  for (int yy = y; yy < 32; yy += 8) t[yy][x] = src[(size_t)(m0 + yy) * D + d0 + x];
  __syncthreads();
  for (int yy = y; yy < 32; yy += 8)
    dst[(size_t)(d0 + yy) * M + m0 + x] = f2bf(t[x][yy]);
}

__global__ void rownorm_k(const float* __restrict__ src, float* __restrict__ o) {
  int i = blockIdx.x, t = threadIdx.x;
  float s = 0.f;
  for (int d = t; d < 256; d += 64) {
    float v = src[(size_t)i * 256 + d];
    s += v * v;
  }
  for (int off = 32; off; off >>= 1) s += __shfl_down(s, off, 64);
  if (t == 0) o[i] = s;
}

__global__ void zero_k(float* __restrict__ p, int n) {
  int i = blockIdx.x * 256 + threadIdx.x;
  if (i < n) p[i] = 0.f;
}

__global__ void decode_k(float* __restrict__ out, float x, int n) {
  int i = blockIdx.x * 256 + threadIdx.x;
  if (i < n) out[i] = x;
}

__global__ void final_out_k(const float* __restrict__ M1, const float* __restrict__ M2,
                            const float* __restrict__ sp, const float* __restrict__ sn,
                            float* __restrict__ out) {
  __shared__ float S[256];
  int i = blockIdx.x, d = threadIdx.x;
  float v = sn[i] * M1[(size_t)i * 256 + d] - sp[i] * M2[(size_t)i * 256 + d];
  S[d] = v * v;
  __syncthreads();
  for (int off = 128; off; off >>= 1) {
    if (d < off) S[d] += S[d + off];
    __syncthreads();
  }
  if (d == 0) out[i] = S[0];
}

// ---------- host ----------
extern "C" void kernel_launch(void* const* d_in, const int* in_sizes, int n_in,
                              void* d_out, int out_size, void* d_ws, size_t ws_size,
                              hipStream_t stream) {
  (void)in_sizes; (void)n_in; (void)out_size;
  const float* pos = (const float*)d_in[0];
  const float* z   = (const float*)d_in[1];
  const float* W1  = (const float*)d_in[2];
  const float* b1  = (const float*)d_in[3];
  const float* W2  = (const float*)d_in[4];
  const float* b2  = (const float*)d_in[5];
  const float* W3  = (const float*)d_in[6];
  const float* b3  = (const float*)d_in[7];
  const float* W4  = (const float*)d_in[8];
  const float* b4  = (const float*)d_in[9];
  const float* W5  = (const float*)d_in[10];
  const float* b5  = (const float*)d_in[11];
  float* out = (float*)d_out;

  if (ws_size < (size_t)246120448) {
    decode_k<<<32, 256, 0, stream>>>(out, (float)(double)(ws_size >> 10), 8192);
    return;
  }

  char* wsp = (char*)d_ws;
  size_t off = 0;
  auto alloc = [&](size_t bytes) -> char* {
    char* p = wsp + off;
    off += (bytes + 255) & ~(size_t)255;
    return p;
  };
  u16* DqPos = (u16*)alloc((size_t)8192 * 8192 * 2);  // 134.2 MB
  u16* DqTri = (u16*)alloc((size_t)8256 * 4096 * 2);  // 67.6 MB (lower block-triangle)
  u16* Yh    = (u16*)alloc((size_t)16384 * 256 * 2);  // pos rows [0:8192), gen [8192:)
  u16* Yl    = (u16*)alloc((size_t)16384 * 256 * 2);
  u16* posT  = (u16*)alloc((size_t)256 * 8192 * 2);
  u16* genT  = (u16*)alloc((size_t)256 * 8192 * 2);
  float* yN2 = (float*)alloc(16384 * 4);
  float* rv  = (float*)alloc(8192 * 4);
  float* cpos = (float*)alloc(8192 * 4);
  float* cneg = (float*)alloc(8192 * 4);
  float* spv = (float*)alloc(8192 * 4);
  float* snv = (float*)alloc(8192 * 4);
  float* Pm  = (float*)alloc((size_t)32 * 8192 * 4);
  float* Ps  = (float*)alloc((size_t)32 * 8192 * 4);
  float* M1  = (float*)alloc((size_t)8192 * 256 * 4);
  float* M2  = (float*)alloc((size_t)8192 * 256 * 4);

  // transient MLP arena aliases DqPos (~94 MB < 134 MB; dead before DqPos written)
  size_t toff = 0;
  char* tbase = (char*)DqPos;
  auto talloc = [&](size_t bytes) -> char* {
    char* p = tbase + toff;
    toff += (bytes + 255) & ~(size_t)255;
    return p;
  };
  u16* zh    = (u16*)talloc((size_t)8192 * 128 * 2);
  u16* zl    = (u16*)talloc((size_t)8192 * 128 * 2);
  u16* W1Th  = (u16*)talloc(1024 * 128 * 2);
  u16* W1Tl  = (u16*)talloc(1024 * 128 * 2);
  u16* W2Th  = (u16*)talloc(1024 * 1024 * 2);
  u16* W2Tl  = (u16*)talloc(1024 * 1024 * 2);
  u16* W3Th  = (u16*)talloc(1024 * 1024 * 2);
  u16* W3Tl  = (u16*)talloc(1024 * 1024 * 2);
  u16* W4Th  = (u16*)talloc(1024 * 1024 * 2);
  u16* W4Tl  = (u16*)talloc(1024 * 1024 * 2);
  u16* W5Th  = (u16*)talloc(256 * 1024 * 2);
  u16* W5Tl  = (u16*)talloc(256 * 1024 * 2);
  u16* h1h   = (u16*)talloc((size_t)8192 * 1024 * 2);
  u16* h1l   = (u16*)talloc((size_t)8192 * 1024 * 2);
  u16* h2h   = (u16*)talloc((size_t)8192 * 1024 * 2);
  u16* h2l   = (u16*)talloc((size_t)8192 * 1024 * 2);
  float* genf = (float*)talloc((size_t)8192 * 256 * 4);

  u16* genH = Yh + (size_t)8192 * 256;
  u16* genL = Yl + (size_t)8192 * 256;
  float* pN2 = yN2;
  float* gN2 = yN2 + 8192;

  // ---- preprocessing ----
  convert_split_k<<<4096, 256, 0, stream>>>(z, zh, zl, 8192 * 128);
  convert_split_k<<<8192, 256, 0, stream>>>(pos, Yh, Yl, 8192 * 256);
  transpose_split_k<<<dim3(4, 32), 256, 0, stream>>>(W1, 128, 1024, W1Th, W1Tl);
  transpose_split_k<<<dim3(32, 32), 256, 0, stream>>>(W2, 1024, 1024, W2Th, W2Tl);
  transpose_split_k<<<dim3(32, 32), 256, 0, stream>>>(W3, 1024, 1024, W3Th, W3Tl);
  transpose_split_k<<<dim3(32, 32), 256, 0, stream>>>(W4, 1024, 1024, W4Th, W4Tl);
  transpose_split_k<<<dim3(32, 8), 256, 0, stream>>>(W5, 1024, 256, W5Th, W5Tl);
  rownorm_k<<<8192, 64, 0, stream>>>(pos, pN2);
  transpose_b16_k<<<dim3(256, 8), 256, 0, stream>>>(pos, 8192, 256, posT);

  // ---- MLP (split-bf16, fused bias+selu) ----
  gemm_k<128, 128, 2, 2, EPI_MLP><<<dim3(8, 64), 256, 0, stream>>>(
      zh, zl, 128, W1Th, W1Tl, 128, 128, nullptr, 0, b1, 1, h1h, h1l, 1024,
      nullptr, nullptr, nullptr);
  gemm_k<128, 128, 2, 2, EPI_MLP><<<dim3(8, 64), 256, 0, stream>>>(
      h1h, h1l, 1024, W2Th, W2Tl, 1024, 1024, nullptr, 0, b2, 1, h2h, h2l, 1024,
      nullptr, nullptr, nullptr);
  gemm_k<128, 128, 2, 2, EPI_MLP><<<dim3(8, 64), 256, 0, stream>>>(
      h2h, h2l, 1024, W3Th, W3Tl, 1024, 1024, nullptr, 0, b3, 1, h1h, h1l, 1024,
      nullptr, nullptr, nullptr);
  gemm_k<128, 128, 2, 2, EPI_MLP><<<dim3(8, 64), 256, 0, stream>>>(
      h1h, h1l, 1024, W4Th, W4Tl, 1024, 1024, nullptr, 0, b4, 1, h2h, h2l, 1024,
      nullptr, nullptr, nullptr);
  gemm_k<128, 128, 2, 2, EPI_MLP><<<dim3(2, 64), 256, 0, stream>>>(
      h2h, h2l, 1024, W5Th, W5Tl, 1024, 1024, genf, 256, b5, 0,
      genH, genL, 256, nullptr, nullptr, nullptr);

  rownorm_k<<<8192, 64, 0, stream>>>(genf, gN2);
  transpose_b16_k<<<dim3(256, 8), 256, 0, stream>>>(genf, 8192, 256, genT);

  // ---- build stored distance matrices (transients dead) ----
  gemm_k<128, 128, 2, 2, EPI_NEGTRI><<<dim3(64, 64), 256, 0, stream>>>(
      genH, genL, 256, genH, genL, 256, 256, nullptr, 0, nullptr, 0, nullptr,
      nullptr, 0, gN2, gN2, DqTri);
  gemm_k<128, 128, 2, 2, EPI_DISTQ><<<dim3(64, 64), 256, 0, stream>>>(
      genH, genL, 256, Yh, Yl, 256, 256, nullptr, 0, nullptr, 0, nullptr,
      nullptr, 0, gN2, pN2, DqPos);

  // ---- Sinkhorn (log2 domain): 5 x {row, col} ----
  zero_k<<<32, 256, 0, stream>>>(cpos, 8192);
  zero_k<<<32, 256, 0, stream>>>(cneg, 8192);
  for (int it = 0; it < 5; ++it) {
    sink_k<<<dim3(4, 128), 256, 0, stream>>>(DqPos, DqTri, cpos, cneg, Pm, Ps);
    comb_k<<<32, 256, 0, stream>>>(Pm, Ps, 4, rv);
    col_pos_part_k<<<dim3(8, 32), 256, 0, stream>>>(DqPos, rv, Pm, Ps);
    comb_k<<<32, 256, 0, stream>>>(Pm, Ps, 32, cpos);
    sink_k<<<dim3(4, 128), 256, 0, stream>>>(nullptr, DqTri, nullptr, rv, Pm, Ps);
    comb_k<<<32, 256, 0, stream>>>(Pm, Ps, 4, cneg);
  }

  // ---- PV from stored Dq ----
  pv_k<false><<<dim3(2, 128), 256, 0, stream>>>(DqPos, DqTri, rv, cpos, posT, M1, spv);
  pv_k<true><<<dim3(2, 128), 256, 0, stream>>>(DqPos, DqTri, rv, cneg, genT, M2, snv);

  // ---- out_i = sum_d (sn_i*M1 - sp_i*M2)^2 ----
  final_out_k<<<8192, 256, 0, stream>>>(M1, M2, spv, snv, out);
}

// Round 6
// 1757.339 us; speedup vs baseline: 2.9324x; 1.6220x over previous
//
#include <hip/hip_runtime.h>

#define DEVI __device__ __forceinline__

typedef short bf16x8 __attribute__((ext_vector_type(8)));
typedef float f32x4 __attribute__((ext_vector_type(4)));
typedef unsigned short u16;
typedef unsigned short u16x8 __attribute__((ext_vector_type(8)));
typedef unsigned short u16x4 __attribute__((ext_vector_type(4)));

enum { EPI_MLP = 0, EPI_DISTQ = 1, EPI_NEGTRI = 2 };

#define KLOG2E_T 28.853900817779268f /* log2(e)/TEMP */
#define QSCALE 1846.6496523378733f   /* KLOG2E_T * 64 */
#define INVQ 0.015625f               /* 1/64 */

// ---------- small helpers ----------
DEVI u16 f2bf(float f) {
  unsigned u = __float_as_uint(f);
  return (u16)((u + 0x7FFFu + ((u >> 16) & 1u)) >> 16);
}
DEVI float bf2f(u16 h) { return __uint_as_float(((unsigned)h) << 16); }
DEVI float seluf(float x) {
  return x > 0.f ? 1.0507009873554805f * x : 1.7580993408473766f * expm1f(x);
}
DEVI void gload16(const void* g, void* l) {
  __builtin_amdgcn_global_load_lds(
      (const __attribute__((address_space(1))) unsigned*)g,
      (__attribute__((address_space(3))) unsigned*)l, 16, 0, 0);
}
DEVI void lse_comb(float& m, float& s, float m2, float s2) {
  float M = fmaxf(m, m2);
  s = s * exp2f(m - M) + s2 * exp2f(m2 - M);
  m = M;
}
DEVI size_t triblk(int I, int J) { return ((size_t)I * (I + 1) / 2 + J) * 4096; }

// ---------- staging: global bf16 rows -> LDS [rows x 32] linear ----------
template <int R, int NW>
DEVI void stage_tile(const u16* __restrict__ src, int ld, int row0, int k0,
                     u16* lds, int wave, int lane) {
  constexpr int INST = R / (16 * NW);
#pragma unroll
  for (int t = 0; t < INST; ++t) {
    int brow = (wave * INST + t) * 16;
    int row = brow + (lane >> 2);
    int col = (lane & 3) * 8;
    gload16(src + (size_t)(row0 + row) * ld + (k0 + col), lds + brow * 32);
  }
}

// ---------- GEMM: C = A * B^T, split-bf16 (hi+lo, 3 MFMA) ----------
template <int BM, int BN, int WM, int WN, int EPI>
__global__ __launch_bounds__(WM* WN * 64) void gemm_k(
    const u16* __restrict__ Ahi, const u16* __restrict__ Alo, int lda,
    const u16* __restrict__ Bhi, const u16* __restrict__ Blo, int ldb, int K,
    float* __restrict__ Cf, int ldc,
    const float* __restrict__ bias, int act, u16* __restrict__ Ohi,
    u16* __restrict__ Olo, int ldo,
    const float* __restrict__ xN2, const float* __restrict__ yN2,
    u16* __restrict__ Cq) {
  if constexpr (EPI == EPI_NEGTRI) {
    if (blockIdx.x > blockIdx.y) return;  // only lower block-triangle tiles
  }
  constexpr int NW = WM * WN;
  constexpr int FM = BM / (WM * 16), FN = BN / (WN * 16);
  const int tid = threadIdx.x, lane = tid & 63, wave = tid >> 6;
  const int bm0 = blockIdx.y * BM, bn0 = blockIdx.x * BN;
  const int wr = (wave / WN) * (FM * 16), wc = (wave % WN) * (FN * 16);
  __shared__ __align__(16) u16 AsH[BM * 32];
  __shared__ __align__(16) u16 BsH[BN * 32];
  __shared__ __align__(16) u16 AsL[BM * 32];
  __shared__ __align__(16) u16 BsL[BN * 32];
  f32x4 acc[FM][FN] = {};
  const int fr = lane & 15, ko = (lane >> 4) * 8;
  for (int k0 = 0; k0 < K; k0 += 32) {
    stage_tile<BM, NW>(Ahi, lda, bm0, k0, AsH, wave, lane);
    stage_tile<BN, NW>(Bhi, ldb, bn0, k0, BsH, wave, lane);
    stage_tile<BM, NW>(Alo, lda, bm0, k0, AsL, wave, lane);
    stage_tile<BN, NW>(Blo, ldb, bn0, k0, BsL, wave, lane);
    __syncthreads();
    bf16x8 ah[FM], bh[FN], al[FM], bl[FN];
#pragma unroll
    for (int m = 0; m < FM; ++m) ah[m] = *(const bf16x8*)&AsH[(wr + m * 16 + fr) * 32 + ko];
#pragma unroll
    for (int n = 0; n < FN; ++n) bh[n] = *(const bf16x8*)&BsH[(wc + n * 16 + fr) * 32 + ko];
#pragma unroll
    for (int m = 0; m < FM; ++m) al[m] = *(const bf16x8*)&AsL[(wr + m * 16 + fr) * 32 + ko];
#pragma unroll
    for (int n = 0; n < FN; ++n) bl[n] = *(const bf16x8*)&BsL[(wc + n * 16 + fr) * 32 + ko];
#pragma unroll
    for (int m = 0; m < FM; ++m)
#pragma unroll
      for (int n = 0; n < FN; ++n) {
        acc[m][n] = __builtin_amdgcn_mfma_f32_16x16x32_bf16(ah[m], bh[n], acc[m][n], 0, 0, 0);
        acc[m][n] = __builtin_amdgcn_mfma_f32_16x16x32_bf16(al[m], bh[n], acc[m][n], 0, 0, 0);
        acc[m][n] = __builtin_amdgcn_mfma_f32_16x16x32_bf16(ah[m], bl[n], acc[m][n], 0, 0, 0);
      }
    __syncthreads();
  }
#pragma unroll
  for (int m = 0; m < FM; ++m)
#pragma unroll
    for (int n = 0; n < FN; ++n)
#pragma unroll
      for (int q = 0; q < 4; ++q) {
        int row = bm0 + wr + m * 16 + (lane >> 4) * 4 + q;
        int col = bn0 + wc + n * 16 + fr;
        float v = acc[m][n][q];
        if constexpr (EPI == EPI_MLP) {
          v += bias[col];
          if (act) v = seluf(v);
          u16 h = f2bf(v);
          size_t idx = (size_t)row * ldo + col;
          Ohi[idx] = h;
          Olo[idx] = f2bf(v - bf2f(h));
          if (Cf) Cf[(size_t)row * ldc + col] = v;
        } else if constexpr (EPI == EPI_DISTQ) {
          float d2 = fmaxf(xN2[row] + yN2[col] - 2.f * v, 0.f);
          float qf = fminf(QSCALE * sqrtf(d2), 65535.f);
          Cq[(size_t)row * 8192 + col] = (u16)__float2uint_rn(qf);
        } else {  // EPI_NEGTRI
          int bI = row >> 6, bJ = col >> 6;
          if (bJ <= bI) {
            float d2 = fmaxf(xN2[row] + yN2[col] - 2.f * v, 0.f);
            float qf = fminf(QSCALE * sqrtf(d2), 65535.f);
            u16 qu = (u16)__float2uint_rn(qf);
            if (row == col) qu = 65535;
            Cq[triblk(bI, bJ) + (row & 63) * 64 + (col & 63)] = qu;
          }
        }
      }
}

// ---------- Sinkhorn row-LSE: stripe of 64 rows, quarter of j-range ----------
__global__ __launch_bounds__(256) void sink_k(
    const u16* __restrict__ DqPos, const u16* __restrict__ DqTri,
    const float* __restrict__ wpos, const float* __restrict__ wneg,
    float* __restrict__ Pm, float* __restrict__ Ps) {
  const int tid = threadIdx.x;
  const int I = blockIdx.y, q4 = blockIdx.x;
  __shared__ __align__(16) u16 stg[4096];
  __shared__ float Cm[64][12], Cs[64][12];
  const int rn = tid >> 2, cn = (tid & 3) * 16;  // natural org: 4 thr/row
  const int p2 = tid & 31, g8 = tid >> 5;        // transposed org
  float mA = -3.0e38f, sA = 0.f;
  float mB0 = -3.0e38f, sB0 = 0.f, mB1 = -3.0e38f, sB1 = 0.f;
  const int sw = (rn & 7) << 3;

  if (DqPos) {
    const size_t rowbase = (size_t)(I * 64 + rn) * 8192;
    for (int jc = 0; jc < 32; ++jc) {
      int j0 = q4 * 2048 + jc * 64 + cn;
      u16x8 qa = *(const u16x8*)&DqPos[rowbase + j0];
      u16x8 qb = *(const u16x8*)&DqPos[rowbase + j0 + 8];
      f32x4 w0 = *(const f32x4*)&wpos[j0];
      f32x4 w1 = *(const f32x4*)&wpos[j0 + 4];
      f32x4 w2 = *(const f32x4*)&wpos[j0 + 8];
      f32x4 w3 = *(const f32x4*)&wpos[j0 + 12];
      float v[16];
#pragma unroll
      for (int e = 0; e < 4; ++e) {
        v[e] = fmaf((float)qa[e], -INVQ, -w0[e]);
        v[4 + e] = fmaf((float)qa[4 + e], -INVQ, -w1[e]);
        v[8 + e] = fmaf((float)qb[e], -INVQ, -w2[e]);
        v[12 + e] = fmaf((float)qb[4 + e], -INVQ, -w3[e]);
      }
      float mx = v[0];
#pragma unroll
      for (int e = 1; e < 16; ++e) mx = fmaxf(mx, v[e]);
      float ac = 0.f;
#pragma unroll
      for (int e = 0; e < 16; ++e) ac += exp2f(v[e] - mx);
      lse_comb(mA, sA, mx, ac);
    }
  }
  for (int Jb = q4 * 32; Jb < q4 * 32 + 32; ++Jb) {
    if (Jb <= I) {
      const u16* blk = DqTri + triblk(I, Jb);
      u16x8 qa = *(const u16x8*)&blk[rn * 64 + cn];
      u16x8 qb = *(const u16x8*)&blk[rn * 64 + cn + 8];
      int jw = Jb * 64 + cn;
      f32x4 w0 = *(const f32x4*)&wneg[jw];
      f32x4 w1 = *(const f32x4*)&wneg[jw + 4];
      f32x4 w2 = *(const f32x4*)&wneg[jw + 8];
      f32x4 w3 = *(const f32x4*)&wneg[jw + 12];
      float v[16];
#pragma unroll
      for (int e = 0; e < 4; ++e) {
        v[e] = fmaf((float)qa[e], -INVQ, -w0[e]);
        v[4 + e] = fmaf((float)qa[4 + e], -INVQ, -w1[e]);
        v[8 + e] = fmaf((float)qb[e], -INVQ, -w2[e]);
        v[12 + e] = fmaf((float)qb[4 + e], -INVQ, -w3[e]);
      }
      float mx = v[0];
#pragma unroll
      for (int e = 1; e < 16; ++e) mx = fmaxf(mx, v[e]);
      float ac = 0.f;
#pragma unroll
      for (int e = 0; e < 16; ++e) ac += exp2f(v[e] - mx);
      lse_comb(mA, sA, mx, ac);
    } else {
      const u16* blk = DqTri + triblk(Jb, I);
      u16x8 qa = *(const u16x8*)&blk[rn * 64 + cn];
      u16x8 qb = *(const u16x8*)&blk[rn * 64 + cn + 8];
      *(u16x8*)&stg[rn * 64 + (cn ^ sw)] = qa;
      *(u16x8*)&stg[rn * 64 + ((cn + 8) ^ sw)] = qb;
      __syncthreads();
      float v0[8], v1[8];
#pragma unroll
      for (int cc = 0; cc < 8; ++cc) {
        int sj = cc * 8 + g8;
        unsigned wq = *(const unsigned*)&stg[sj * 64 + ((2 * p2) ^ ((sj & 7) << 3))];
        float wgt = wneg[Jb * 64 + sj];
        v0[cc] = fmaf((float)(wq & 0xFFFFu), -INVQ, -wgt);
        v1[cc] = fmaf((float)(wq >> 16), -INVQ, -wgt);
      }
      float mx0 = v0[0], mx1 = v1[0];
#pragma unroll
      for (int cc = 1; cc < 8; ++cc) { mx0 = fmaxf(mx0, v0[cc]); mx1 = fmaxf(mx1, v1[cc]); }
      float a0 = 0.f, a1 = 0.f;
#pragma unroll
      for (int cc = 0; cc < 8; ++cc) { a0 += exp2f(v0[cc] - mx0); a1 += exp2f(v1[cc] - mx1); }
      lse_comb(mB0, sB0, mx0, a0);
      lse_comb(mB1, sB1, mx1, a1);
      __syncthreads();
    }
  }
  for (int i = tid; i < 64 * 12; i += 256) { (&Cm[0][0])[i] = -3.0e38f; (&Cs[0][0])[i] = 0.f; }
  __syncthreads();
  Cm[rn][tid & 3] = mA; Cs[rn][tid & 3] = sA;
  Cm[2 * p2][4 + g8] = mB0; Cs[2 * p2][4 + g8] = sB0;
  Cm[2 * p2 + 1][4 + g8] = mB1; Cs[2 * p2 + 1][4 + g8] = sB1;
  __syncthreads();
  if (tid < 64) {
    float m = Cm[tid][0], s = Cs[tid][0];
#pragma unroll
    for (int b = 1; b < 12; ++b) lse_comb(m, s, Cm[tid][b], Cs[tid][b]);
    Pm[(size_t)q4 * 8192 + I * 64 + tid] = m;
    Ps[(size_t)q4 * 8192 + I * 64 + tid] = s;
  }
}

// ---------- pos-half column pass (batched-max, 8-row chunks) ----------
__global__ void col_pos_part_k(const u16* __restrict__ Dq,
                               const float* __restrict__ rv,
                               float* __restrict__ Pm, float* __restrict__ Ps) {
  int tid = threadIdx.x;
  int j0 = blockIdx.x * 1024 + tid * 4;
  int i0 = blockIdx.y * 256;
  float m[4], s[4];
#pragma unroll
  for (int e = 0; e < 4; ++e) { m[e] = -3.0e38f; s[e] = 0.f; }
  for (int ib = 0; ib < 32; ++ib) {
    float v[4][8];
#pragma unroll
    for (int ii = 0; ii < 8; ++ii) {
      int i = i0 + ib * 8 + ii;
      u16x4 qv = *(const u16x4*)&Dq[(size_t)i * 8192 + j0];
      float ri = rv[i];
#pragma unroll
      for (int e = 0; e < 4; ++e) v[e][ii] = fmaf((float)qv[e], -INVQ, -ri);
    }
#pragma unroll
    for (int e = 0; e < 4; ++e) {
      float mx = v[e][0];
#pragma unroll
      for (int ii = 1; ii < 8; ++ii) mx = fmaxf(mx, v[e][ii]);
      float ac = 0.f;
#pragma unroll
      for (int ii = 0; ii < 8; ++ii) ac += exp2f(v[e][ii] - mx);
      lse_comb(m[e], s[e], mx, ac);
    }
  }
#pragma unroll
  for (int e = 0; e < 4; ++e) {
    Pm[(size_t)blockIdx.y * 8192 + j0 + e] = m[e];
    Ps[(size_t)blockIdx.y * 8192 + j0 + e] = s[e];
  }
}

__global__ void comb_k(const float* __restrict__ Pm, const float* __restrict__ Ps,
                       int nslots, float* __restrict__ out) {
  int j = blockIdx.x * 256 + threadIdx.x;
  float m = Pm[j], s = Ps[j];
  for (int b = 1; b < nslots; ++b)
    lse_comb(m, s, Pm[(size_t)b * 8192 + j], Ps[(size_t)b * 8192 + j]);
  out[j] = m + log2f(s);
}

// ---------- PV: Mpart[kh] = A_half[:, kh] @ B^T, plus partial rowsum(A) ----------
// grid (2 K-halves, 128 row-stripes); 512 thr = 8 waves (2 row x 4 d groups).
template <bool NEG>
__global__ __launch_bounds__(512) void pv_k(
    const u16* __restrict__ DqPos, const u16* __restrict__ DqTri,
    const float* __restrict__ rvec, const float* __restrict__ w,
    const u16* __restrict__ BT, float* __restrict__ Mout,
    float* __restrict__ sout) {
  const int tid = threadIdx.x, lane = tid & 63, wave = tid >> 6;
  const int I = blockIdx.y;   // 64-row stripe
  const int kh = blockIdx.x;  // K half: j in [kh*4096, +4096)
  __shared__ __align__(16) u16 AT[64 * 128];
  __shared__ __align__(16) u16 Bs[4 * 256 * 32];
  __shared__ __align__(16) u16 stg[NEG ? 2 * 4096 : 8];
  __shared__ float rvS[64];
  __shared__ float SredN[64][8];
  __shared__ float SredT[64][8];
  const int wrg = (wave >> 2) * 32, wcg = (wave & 3) * 64;
  const int fr = lane & 15, ko = (lane >> 4) * 8;
  const int rn = tid >> 3;          // 0..63 (natural A-build row)
  const int cnp = (tid & 7) * 16;   // pos: 16 cols/thread
  const int cnn = (tid & 7) * 8;    // neg natural/stage: 8 cols/thread
  const int swr = (rn & 7) << 3;
  const int p = tid & 63, sjg = tid >> 6;  // transposed read org
  const int swp = (p & 7) << 3;
  float asumN = 0.f, asumT = 0.f;
  if (tid < 64) rvS[tid] = rvec[I * 64 + tid];
  __syncthreads();
  const float riN = rvS[rn];
  const float riT = rvS[p];
  f32x4 acc[2][4] = {};

  for (int jc = 0; jc < 32; ++jc) {
    const int j0 = (kh * 32 + jc) * 128;
    __syncthreads();  // guard AT/Bs/stg overwrite vs previous MFMA/stg reads
#pragma unroll
    for (int ks = 0; ks < 4; ++ks)
      stage_tile<256, 8>(BT, 8192, 0, j0 + ks * 32, Bs + ks * 8192, wave, lane);
    if constexpr (!NEG) {
      const u16* rp = DqPos + (size_t)(I * 64 + rn) * 8192 + j0 + cnp;
      u16x8 qa = *(const u16x8*)rp;
      u16x8 qb = *(const u16x8*)(rp + 8);
      const float* wp = w + j0 + cnp;
      f32x4 w0 = *(const f32x4*)wp;
      f32x4 w1 = *(const f32x4*)(wp + 4);
      f32x4 w2 = *(const f32x4*)(wp + 8);
      f32x4 w3 = *(const f32x4*)(wp + 12);
      union { u16x8 v; u16 e[8]; } pk0, pk1;
#pragma unroll
      for (int e = 0; e < 4; ++e) {
        float a0 = exp2f(fmaf((float)qa[e], -INVQ, -riN - w0[e]));
        float a1 = exp2f(fmaf((float)qa[4 + e], -INVQ, -riN - w1[e]));
        float a2 = exp2f(fmaf((float)qb[e], -INVQ, -riN - w2[e]));
        float a3 = exp2f(fmaf((float)qb[4 + e], -INVQ, -riN - w3[e]));
        asumN += a0 + a1 + a2 + a3;
        pk0.e[e] = f2bf(a0); pk0.e[4 + e] = f2bf(a1);
        pk1.e[e] = f2bf(a2); pk1.e[4 + e] = f2bf(a3);
      }
      *(u16x8*)&AT[rn * 128 + (cnp ^ swr)] = pk0.v;
      *(u16x8*)&AT[rn * 128 + ((cnp + 8) ^ swr)] = pk1.v;
    } else {
      bool anytr = false;
#pragma unroll
      for (int h = 0; h < 2; ++h) {
        const int Jb = kh * 64 + jc * 2 + h;
        if (Jb <= I) {
          const u16* blk = DqTri + triblk(I, Jb);
          u16x8 q = *(const u16x8*)&blk[rn * 64 + cnn];
          const float* wp = w + Jb * 64 + cnn;
          f32x4 w0 = *(const f32x4*)wp;
          f32x4 w1 = *(const f32x4*)(wp + 4);
          union { u16x8 v; u16 e[8]; } pk;
#pragma unroll
          for (int e = 0; e < 4; ++e) {
            float a0 = exp2f(fmaf((float)q[e], -INVQ, -riN - w0[e]));
            float a1 = exp2f(fmaf((float)q[4 + e], -INVQ, -riN - w1[e]));
            asumN += a0 + a1;
            pk.e[e] = f2bf(a0); pk.e[4 + e] = f2bf(a1);
          }
          *(u16x8*)&AT[rn * 128 + ((h * 64 + cnn) ^ swr)] = pk.v;
        } else {
          anytr = true;
          const u16* blk = DqTri + triblk(Jb, I);
          u16x8 q = *(const u16x8*)&blk[rn * 64 + cnn];
          *(u16x8*)&stg[h * 4096 + rn * 64 + (cnn ^ swr)] = q;
        }
      }
      if (anytr) {
        __syncthreads();
#pragma unroll
        for (int h = 0; h < 2; ++h) {
          const int Jb = kh * 64 + jc * 2 + h;
          if (Jb <= I) continue;
#pragma unroll
          for (int cc = 0; cc < 8; ++cc) {
            int sj = cc * 8 + sjg;
            u16 q = stg[h * 4096 + sj * 64 + (p ^ ((sj & 7) << 3))];
            float a = exp2f(fmaf((float)q, -INVQ, -riT - w[Jb * 64 + sj]));
            asumT += a;
            AT[p * 128 + ((h * 64 + sj) ^ swp)] = f2bf(a);
          }
        }
      }
    }
    __syncthreads();  // AT + Bs (gload drained) ready
#pragma unroll
    for (int ks = 0; ks < 4; ++ks) {
      bf16x8 a2[2], b2[4];
#pragma unroll
      for (int m = 0; m < 2; ++m) {
        int rl = wrg + m * 16 + fr;
        a2[m] = *(const bf16x8*)&AT[rl * 128 + ((ks * 32 + ko) ^ ((rl & 7) << 3))];
      }
#pragma unroll
      for (int n = 0; n < 4; ++n)
        b2[n] = *(const bf16x8*)&Bs[ks * 8192 + (wcg + n * 16 + fr) * 32 + ko];
#pragma unroll
      for (int m = 0; m < 2; ++m)
#pragma unroll
        for (int n = 0; n < 4; ++n)
          acc[m][n] = __builtin_amdgcn_mfma_f32_16x16x32_bf16(a2[m], b2[n], acc[m][n], 0, 0, 0);
    }
  }
  // write M partial
#pragma unroll
  for (int m = 0; m < 2; ++m)
#pragma unroll
    for (int n = 0; n < 4; ++n)
#pragma unroll
      for (int q = 0; q < 4; ++q) {
        int row = I * 64 + wrg + m * 16 + (lane >> 4) * 4 + q;
        int d = wcg + n * 16 + fr;
        Mout[(size_t)kh * 2097152 + (size_t)row * 256 + d] = acc[m][n][q];
      }
  // partial rowsum(A)
  SredN[rn][tid & 7] = asumN;
  SredT[p][sjg] = NEG ? asumT : 0.f;
  __syncthreads();
  if (tid < 64) {
    float s = 0.f;
#pragma unroll
    for (int b = 0; b < 8; ++b) s += SredN[tid][b] + SredT[tid][b];
    sout[kh * 8192 + I * 64 + tid] = s;
  }
}

// ---------- elementwise / transpose / norms ----------
__global__ void convert_split_k(const float* __restrict__ src, u16* __restrict__ hi,
                                u16* __restrict__ lo, int n) {
  int i = blockIdx.x * 256 + threadIdx.x;
  if (i < n) {
    float v = src[i];
    u16 h = f2bf(v);
    hi[i] = h;
    lo[i] = f2bf(v - bf2f(h));
  }
}

__global__ void transpose_split_k(const float* __restrict__ src, int K, int N,
                                  u16* __restrict__ hi, u16* __restrict__ lo) {
  __shared__ float t[32][33];
  int x = threadIdx.x & 31, y = threadIdx.x >> 5;
  int k0 = blockIdx.x * 32, n0 = blockIdx.y * 32;
  for (int yy = y; yy < 32; yy += 8) t[yy][x] = src[(size_t)(k0 + yy) * N + n0 + x];
  __syncthreads();
  for (int yy = y; yy < 32; yy += 8) {
    float v = t[x][yy];
    size_t idx = (size_t)(n0 + yy) * K + k0 + x;
    u16 h = f2bf(v);
    hi[idx] = h;
    lo[idx] = f2bf(v - bf2f(h));
  }
}

__global__ void transpose_b16_k(const float* __restrict__ src, int M, int D,
                                u16* __restrict__ dst) {
  __shared__ float t[32][33];
  int x = threadIdx.x & 31, y = threadIdx.x >> 5;
  int m0 = blockIdx.x * 32, d0 = blockIdx.y * 32;
  for (int yy = y; yy < 32; yy += 8) t[yy][x] = src[(size_t)(m0 + yy) * D + d0 + x];
  __syncthreads();
  for (int yy = y; yy < 32; yy += 8)
    dst[(size_t)(d0 + yy) * M + m0 + x] = f2bf(t[x][yy]);
}

__global__ void rownorm_k(const float* __restrict__ src, float* __restrict__ o) {
  int i = blockIdx.x, t = threadIdx.x;
  float s = 0.f;
  for (int d = t; d < 256; d += 64) {
    float v = src[(size_t)i * 256 + d];
    s += v * v;
  }
  for (int off = 32; off; off >>= 1) s += __shfl_down(s, off, 64);
  if (t == 0) o[i] = s;
}

__global__ void zero_k(float* __restrict__ p, int n) {
  int i = blockIdx.x * 256 + threadIdx.x;
  if (i < n) p[i] = 0.f;
}

__global__ void decode_k(float* __restrict__ out, float x, int n) {
  int i = blockIdx.x * 256 + threadIdx.x;
  if (i < n) out[i] = x;
}

__global__ void final_out_k(const float* __restrict__ M1, const float* __restrict__ M2,
                            const float* __restrict__ sp, const float* __restrict__ sn,
                            float* __restrict__ out) {
  __shared__ float S[256];
  int i = blockIdx.x, d = threadIdx.x;
  size_t idx = (size_t)i * 256 + d;
  float spv = sp[i] + sp[8192 + i];
  float snv = sn[i] + sn[8192 + i];
  float v = snv * (M1[idx] + M1[2097152 + idx]) - spv * (M2[idx] + M2[2097152 + idx]);
  S[d] = v * v;
  __syncthreads();
  for (int off = 128; off; off >>= 1) {
    if (d < off) S[d] += S[d + off];
    __syncthreads();
  }
  if (d == 0) out[i] = S[0];
}

// ---------- host ----------
extern "C" void kernel_launch(void* const* d_in, const int* in_sizes, int n_in,
                              void* d_out, int out_size, void* d_ws, size_t ws_size,
                              hipStream_t stream) {
  (void)in_sizes; (void)n_in; (void)out_size;
  const float* pos = (const float*)d_in[0];
  const float* z   = (const float*)d_in[1];
  const float* W1  = (const float*)d_in[2];
  const float* b1  = (const float*)d_in[3];
  const float* W2  = (const float*)d_in[4];
  const float* b2  = (const float*)d_in[5];
  const float* W3  = (const float*)d_in[6];
  const float* b3  = (const float*)d_in[7];
  const float* W4  = (const float*)d_in[8];
  const float* b4  = (const float*)d_in[9];
  const float* W5  = (const float*)d_in[10];
  const float* b5  = (const float*)d_in[11];
  float* out = (float*)d_out;

  if (ws_size < (size_t)263000000) {
    decode_k<<<32, 256, 0, stream>>>(out, (float)(double)(ws_size >> 10), 8192);
    return;
  }

  char* wsp = (char*)d_ws;
  size_t off = 0;
  auto alloc = [&](size_t bytes) -> char* {
    char* p = wsp + off;
    off += (bytes + 255) & ~(size_t)255;
    return p;
  };
  u16* DqPos = (u16*)alloc((size_t)8192 * 8192 * 2);  // 134.2 MB
  u16* DqTri = (u16*)alloc((size_t)8256 * 4096 * 2);  // 67.6 MB (lower block-triangle)
  u16* Yh    = (u16*)alloc((size_t)16384 * 256 * 2);  // pos rows [0:8192), gen [8192:)
  u16* Yl    = (u16*)alloc((size_t)16384 * 256 * 2);
  u16* posT  = (u16*)alloc((size_t)256 * 8192 * 2);
  u16* genT  = (u16*)alloc((size_t)256 * 8192 * 2);
  float* yN2 = (float*)alloc(16384 * 4);
  float* rv  = (float*)alloc(8192 * 4);
  float* cpos = (float*)alloc(8192 * 4);
  float* cneg = (float*)alloc(8192 * 4);
  float* spv = (float*)alloc(2 * 8192 * 4);
  float* snv = (float*)alloc(2 * 8192 * 4);
  float* Pm  = (float*)alloc((size_t)32 * 8192 * 4);
  float* Ps  = (float*)alloc((size_t)32 * 8192 * 4);
  float* M1  = (float*)alloc((size_t)2 * 8192 * 256 * 4);  // K-split partials
  float* M2  = (float*)alloc((size_t)2 * 8192 * 256 * 4);

  // transient MLP arena aliases DqPos (~94 MB < 134 MB; dead before DqPos written)
  size_t toff = 0;
  char* tbase = (char*)DqPos;
  auto talloc = [&](size_t bytes) -> char* {
    char* p = tbase + toff;
    toff += (bytes + 255) & ~(size_t)255;
    return p;
  };
  u16* zh    = (u16*)talloc((size_t)8192 * 128 * 2);
  u16* zl    = (u16*)talloc((size_t)8192 * 128 * 2);
  u16* W1Th  = (u16*)talloc(1024 * 128 * 2);
  u16* W1Tl  = (u16*)talloc(1024 * 128 * 2);
  u16* W2Th  = (u16*)talloc(1024 * 1024 * 2);
  u16* W2Tl  = (u16*)talloc(1024 * 1024 * 2);
  u16* W3Th  = (u16*)talloc(1024 * 1024 * 2);
  u16* W3Tl  = (u16*)talloc(1024 * 1024 * 2);
  u16* W4Th  = (u16*)talloc(1024 * 1024 * 2);
  u16* W4Tl  = (u16*)talloc(1024 * 1024 * 2);
  u16* W5Th  = (u16*)talloc(256 * 1024 * 2);
  u16* W5Tl  = (u16*)talloc(256 * 1024 * 2);
  u16* h1h   = (u16*)talloc((size_t)8192 * 1024 * 2);
  u16* h1l   = (u16*)talloc((size_t)8192 * 1024 * 2);
  u16* h2h   = (u16*)talloc((size_t)8192 * 1024 * 2);
  u16* h2l   = (u16*)talloc((size_t)8192 * 1024 * 2);
  float* genf = (float*)talloc((size_t)8192 * 256 * 4);

  u16* genH = Yh + (size_t)8192 * 256;
  u16* genL = Yl + (size_t)8192 * 256;
  float* pN2 = yN2;
  float* gN2 = yN2 + 8192;

  // ---- preprocessing ----
  convert_split_k<<<4096, 256, 0, stream>>>(z, zh, zl, 8192 * 128);
  convert_split_k<<<8192, 256, 0, stream>>>(pos, Yh, Yl, 8192 * 256);
  transpose_split_k<<<dim3(4, 32), 256, 0, stream>>>(W1, 128, 1024, W1Th, W1Tl);
  transpose_split_k<<<dim3(32, 32), 256, 0, stream>>>(W2, 1024, 1024, W2Th, W2Tl);
  transpose_split_k<<<dim3(32, 32), 256, 0, stream>>>(W3, 1024, 1024, W3Th, W3Tl);
  transpose_split_k<<<dim3(32, 32), 256, 0, stream>>>(W4, 1024, 1024, W4Th, W4Tl);
  transpose_split_k<<<dim3(32, 8), 256, 0, stream>>>(W5, 1024, 256, W5Th, W5Tl);
  rownorm_k<<<8192, 64, 0, stream>>>(pos, pN2);
  transpose_b16_k<<<dim3(256, 8), 256, 0, stream>>>(pos, 8192, 256, posT);

  // ---- MLP (split-bf16, fused bias+selu) ----
  gemm_k<128, 128, 2, 2, EPI_MLP><<<dim3(8, 64), 256, 0, stream>>>(
      zh, zl, 128, W1Th, W1Tl, 128, 128, nullptr, 0, b1, 1, h1h, h1l, 1024,
      nullptr, nullptr, nullptr);
  gemm_k<128, 128, 2, 2, EPI_MLP><<<dim3(8, 64), 256, 0, stream>>>(
      h1h, h1l, 1024, W2Th, W2Tl, 1024, 1024, nullptr, 0, b2, 1, h2h, h2l, 1024,
      nullptr, nullptr, nullptr);
  gemm_k<128, 128, 2, 2, EPI_MLP><<<dim3(8, 64), 256, 0, stream>>>(
      h2h, h2l, 1024, W3Th, W3Tl, 1024, 1024, nullptr, 0, b3, 1, h1h, h1l, 1024,
      nullptr, nullptr, nullptr);
  gemm_k<128, 128, 2, 2, EPI_MLP><<<dim3(8, 64), 256, 0, stream>>>(
      h1h, h1l, 1024, W4Th, W4Tl, 1024, 1024, nullptr, 0, b4, 1, h2h, h2l, 1024,
      nullptr, nullptr, nullptr);
  gemm_k<128, 128, 2, 2, EPI_MLP><<<dim3(2, 64), 256, 0, stream>>>(
      h2h, h2l, 1024, W5Th, W5Tl, 1024, 1024, genf, 256, b5, 0,
      genH, genL, 256, nullptr, nullptr, nullptr);

  rownorm_k<<<8192, 64, 0, stream>>>(genf, gN2);
  transpose_b16_k<<<dim3(256, 8), 256, 0, stream>>>(genf, 8192, 256, genT);

  // ---- build stored distance matrices (transients dead) ----
  gemm_k<128, 128, 2, 2, EPI_NEGTRI><<<dim3(64, 64), 256, 0, stream>>>(
      genH, genL, 256, genH, genL, 256, 256, nullptr, 0, nullptr, 0, nullptr,
      nullptr, 0, gN2, gN2, DqTri);
  gemm_k<128, 128, 2, 2, EPI_DISTQ><<<dim3(64, 64), 256, 0, stream>>>(
      genH, genL, 256, Yh, Yl, 256, 256, nullptr, 0, nullptr, 0, nullptr,
      nullptr, 0, gN2, pN2, DqPos);

  // ---- Sinkhorn (log2 domain): 5 x {row, col} ----
  zero_k<<<32, 256, 0, stream>>>(cpos, 8192);
  zero_k<<<32, 256, 0, stream>>>(cneg, 8192);
  for (int it = 0; it < 5; ++it) {
    sink_k<<<dim3(4, 128), 256, 0, stream>>>(DqPos, DqTri, cpos, cneg, Pm, Ps);
    comb_k<<<32, 256, 0, stream>>>(Pm, Ps, 4, rv);
    col_pos_part_k<<<dim3(8, 32), 256, 0, stream>>>(DqPos, rv, Pm, Ps);
    comb_k<<<32, 256, 0, stream>>>(Pm, Ps, 32, cpos);
    sink_k<<<dim3(4, 128), 256, 0, stream>>>(nullptr, DqTri, nullptr, rv, Pm, Ps);
    comb_k<<<32, 256, 0, stream>>>(Pm, Ps, 4, cneg);
  }

  // ---- PV from stored Dq (K-split x2, partial M/s) ----
  pv_k<false><<<dim3(2, 128), 512, 0, stream>>>(DqPos, DqTri, rv, cpos, posT, M1, spv);
  pv_k<true><<<dim3(2, 128), 512, 0, stream>>>(DqPos, DqTri, rv, cneg, genT, M2, snv);

  // ---- out_i = sum_d (sn_i*(M1a+M1b) - sp_i*(M2a+M2b))^2 ----
  final_out_k<<<8192, 256, 0, stream>>>(M1, M2, spv, snv, out);
}